// Round 4
// baseline (5726.345 us; speedup 1.0000x reference)
//
#include <hip/hip_runtime.h>
#include <hip/hip_bf16.h>

#define N_NODES 8000
#define N_EDGES 64000
#define NBATCH  64
#define NGRID   12
#define HIDC    128
#define NPB     4        // recv-nodes per edge-block

typedef __bf16 bf16x8 __attribute__((ext_vector_type(8)));
typedef float  f32x4  __attribute__((ext_vector_type(4)));

__device__ __forceinline__ float gelu_f(float x) {
    return 0.5f * x * (1.0f + erff(x * 0.70710678118654752440f));
}

// ---------------- grid0 + per-batch rotated grids ----------------
__global__ void k_grid(const float* __restrict__ Q, float* __restrict__ grid0,
                       float* __restrict__ grid) {
    int t = threadIdx.x;
    __shared__ float g0[12][3];
    if (t < 12) {
        float fi = (float)t;
        float theta = 6.28318530717958647692f * fi / 1.61803398874989484820f;
        float z = 1.0f - (2.0f * fi + 1.0f) / 12.0f;
        float r = sqrtf(fmaxf(1.0f - z * z, 0.0f));
        g0[t][0] = r * cosf(theta);
        g0[t][1] = r * sinf(theta);
        g0[t][2] = z;
        grid0[t * 3 + 0] = g0[t][0];
        grid0[t * 3 + 1] = g0[t][1];
        grid0[t * 3 + 2] = g0[t][2];
    }
    __syncthreads();
    for (int idx = t; idx < NBATCH * 12 * 3; idx += blockDim.x) {
        int b = idx / 36, rmd = idx % 36, n = rmd / 3, i = rmd % 3;
        float acc = 0.f;
        #pragma unroll
        for (int j = 0; j < 3; ++j) acc += Q[b * 9 + i * 3 + j] * g0[n][j];
        grid[idx] = acc;
    }
}

// ---------------- kb_sh -> fk  (3,12,12,128) ----------------
__global__ __launch_bounds__(128) void k_kbsh(
    const float* __restrict__ grid0,
    const float* __restrict__ Wsh1, const float* __restrict__ bsh1,
    const float* __restrict__ Wsh2, const float* __restrict__ bsh2,
    const float* __restrict__ Wfk, float* __restrict__ fk) {
    int row = blockIdx.x;            // p*12+o
    int p = row / 12, o = row % 12, t = threadIdx.x;
    float tt = grid0[p*3]*grid0[o*3] + grid0[p*3+1]*grid0[o*3+1] + grid0[p*3+2]*grid0[o*3+2];
    float p1 = tt, p2 = tt * tt, p3 = p2 * tt;
    float h1 = gelu_f(p1 * Wsh1[t] + p2 * Wsh1[128 + t] + p3 * Wsh1[256 + t] + bsh1[t]);
    __shared__ float h1S[128];
    __shared__ float h2S[128];
    h1S[t] = h1;
    __syncthreads();
    float acc = bsh2[t];
    #pragma unroll 8
    for (int k = 0; k < 128; ++k) acc += h1S[k] * Wsh2[k * 128 + t];
    h2S[t] = gelu_f(acc);
    __syncthreads();
    for (int l = 0; l < 3; ++l) {
        float a = 0.f;
        #pragma unroll 8
        for (int k = 0; k < 128; ++k) a += h2S[k] * Wfk[l * 16384 + k * 128 + t];
        fk[l * 18432 + row * 128 + t] = a;
    }
}

// ---------------- node_grid + h0 = f @ Wemb (h stored bf16) ----------------
__global__ __launch_bounds__(128) void k_embed(
    const float* __restrict__ x, const float* __restrict__ vec,
    const int* __restrict__ batch, const float* __restrict__ grid,
    const float* __restrict__ Wemb, float* __restrict__ node_grid,
    __bf16* __restrict__ h_bf) {
    __shared__ float WembS[18 * 128];
    __shared__ float ngS[36];
    __shared__ float xS[16];
    __shared__ float vS[6];
    int n = blockIdx.x, t = threadIdx.x;
    for (int i = t; i < 18 * 128; i += 128) WembS[i] = Wemb[i];
    int b = batch[n];
    if (t < 36) { float g = grid[b * 36 + t]; ngS[t] = g; node_grid[n * 36 + t] = g; }
    if (t < 16) xS[t] = x[n * 16 + t];
    if (t >= 16 && t < 22) vS[t - 16] = vec[n * 6 + (t - 16)];
    __syncthreads();
    for (int g = 0; g < NGRID; ++g) {
        float g0 = ngS[g*3], g1 = ngS[g*3+1], g2 = ngS[g*3+2];
        float xv0 = vS[0]*g0 + vS[1]*g1 + vS[2]*g2;
        float xv1 = vS[3]*g0 + vS[4]*g1 + vS[5]*g2;
        float acc = xv0 * WembS[16*128 + t] + xv1 * WembS[17*128 + t];
        #pragma unroll
        for (int j = 0; j < 16; ++j) acc += xS[j] * WembS[j*128 + t];
        h_bf[((size_t)n * NGRID + g) * HIDC + t] = (__bf16)acc;
    }
}

// ---------------- CSR build: degree count ----------------
__global__ __launch_bounds__(256) void k_deg(const int* __restrict__ recv,
                                             int* __restrict__ deg) {
    int e = blockIdx.x * 256 + threadIdx.x;
    if (e < N_EDGES) atomicAdd(&deg[recv[e]], 1);
}

// ---------------- CSR build: single-block scan ----------------
__global__ __launch_bounds__(1024) void k_scan(const int* __restrict__ deg,
                                               int* __restrict__ rowptr,
                                               int* __restrict__ cursor) {
    __shared__ int part[1024];
    int t = threadIdx.x;
    int base = t * 8;
    int local[8];
    int s = 0;
    #pragma unroll
    for (int j = 0; j < 8; ++j) {
        int idx = base + j;
        int v = (idx < N_NODES) ? deg[idx] : 0;
        local[j] = s;
        s += v;
    }
    part[t] = s;
    __syncthreads();
    for (int off = 1; off < 1024; off <<= 1) {
        int v = (t >= off) ? part[t - off] : 0;
        __syncthreads();
        part[t] += v;
        __syncthreads();
    }
    int excl = (t == 0) ? 0 : part[t - 1];
    #pragma unroll
    for (int j = 0; j < 8; ++j) {
        int idx = base + j;
        if (idx < N_NODES) {
            int v = excl + local[j];
            rowptr[idx] = v;
            cursor[idx] = v;
        }
    }
    if (t == 1023) rowptr[N_NODES] = part[1023];
}

// ---------------- CSR build: fill permutation ----------------
__global__ __launch_bounds__(256) void k_fill(const int* __restrict__ recv,
                                              int* __restrict__ cursor,
                                              int* __restrict__ perm) {
    int e = blockIdx.x * 256 + threadIdx.x;
    if (e < N_EDGES) {
        int r = recv[e];
        int p = atomicAdd(&cursor[r], 1);
        perm[p] = e;
    }
}

// ---------------- per-(sorted-edge,grid) invariants + sorted send ----------------
__global__ __launch_bounds__(256) void k_attr_sorted(
    const float* __restrict__ pos, const float* __restrict__ ng,
    const int* __restrict__ send, const int* __restrict__ recv,
    const int* __restrict__ perm,
    float* __restrict__ attr_s, int* __restrict__ send_s) {
    int idx = blockIdx.x * 256 + threadIdx.x;
    if (idx >= (N_EDGES + 16) * 12) return;
    int i = idx / 12, g = idx % 12;
    if (i < N_EDGES) {
        int e = perm[i];
        int s = send[e], r = recv[e];
        float rx = pos[s*3+0] - pos[r*3+0];
        float ry = pos[s*3+1] - pos[r*3+1];
        float rz = pos[s*3+2] - pos[r*3+2];
        const float* gr = ng + ((size_t)r * 12 + g) * 3;
        float g0 = gr[0], g1 = gr[1], g2 = gr[2];
        float iv1 = rx*g0 + ry*g1 + rz*g2;
        float wx = rx - iv1*g0, wy = ry - iv1*g1, wz = rz - iv1*g2;
        attr_s[(size_t)idx * 2 + 0] = iv1;
        attr_s[(size_t)idx * 2 + 1] = sqrtf(wx*wx + wy*wy + wz*wz);
        if (g == 0) send_s[i] = s;
    } else {
        attr_s[(size_t)idx * 2 + 0] = 0.f;
        attr_s[(size_t)idx * 2 + 1] = 0.f;
        if (g == 0) send_s[i] = 0;
    }
}

// ---------------- transpose + bf16-convert weights: WT[0]=Wsp2T, WT[1..3]=WkT[l] ----------------
__global__ __launch_bounds__(256) void k_prepw(const float* __restrict__ Wsp2,
                                               const float* __restrict__ Wk,
                                               __bf16* __restrict__ WT) {
    int i = blockIdx.x * 256 + threadIdx.x;
    if (i >= 4 * 16384) return;
    int buf = i >> 14, r = i & 16383;
    int n = r >> 7, k = r & 127;
    float v = (buf == 0) ? Wsp2[k * 128 + n] : Wk[(buf - 1) * 16384 + k * 128 + n];
    WT[i] = (__bf16)v;
}

// ---------------- per-layer fused edge kernel: CSR gather, LDS-atomic agg ----------------
// Block owns NPB=4 recv nodes (contiguous sorted edges). Per 16-edge tile:
// poly->h1 (bf16, LDS), GEMM1 (x Wsp2) + gelu writeback, GEMM2 (x Wk[l]),
// epilogue msg = h_bf[send]*k accumulated into per-block LDS agg via ds_add.
// One coalesced store of agg at the end; zero global atomics.
__global__ __launch_bounds__(256, 2) void k_edge_csr(
    const float* __restrict__ attr_s, const int* __restrict__ send_s,
    const int* __restrict__ rowptr,
    const __bf16* __restrict__ W2T, const __bf16* __restrict__ WkTl,
    const float* __restrict__ Wsp1, const float* __restrict__ bsp1,
    const float* __restrict__ bsp2,
    const __bf16* __restrict__ h_bf, float* __restrict__ agg) {
    __shared__ __align__(16) __bf16 A_lds[192 * 136];
    __shared__ float aggS[NPB * 1536];
    __shared__ int sendS[16], nlS[16];
    int t = threadIdx.x;
    int lane = t & 63, w = t >> 6;
    int l15 = lane & 15, quad = lane >> 4;
    int n0 = blockIdx.x * NPB;
    int rp0 = rowptr[n0];
    int cnt = rowptr[n0 + NPB] - rp0;

    for (int i = t; i < NPB * 1536; i += 256) aggS[i] = 0.f;

    // per-thread poly weights for column c (combined poly_features duplicates)
    int c = t & 127, rh = t >> 7;
    float w_a, w_b, w_aa, w_ab, w_bb, w_aaa, w_aab, w_abb, w_bbb, b1v;
    {
        float w1[14];
        #pragma unroll
        for (int j = 0; j < 14; ++j) w1[j] = Wsp1[j * 128 + c];
        w_a = w1[0]; w_b = w1[1];
        w_aa = w1[2]; w_ab = w1[3] + w1[4]; w_bb = w1[5];
        w_aaa = w1[6]; w_aab = w1[7] + w1[8] + w1[10];
        w_abb = w1[9] + w1[11] + w1[12]; w_bbb = w1[13];
        b1v = bsp1[c];
    }
    float b2v[8];
    #pragma unroll
    for (int nt = 0; nt < 8; ++nt) b2v[nt] = bsp2[nt * 16 + l15];

    int ntiles = (cnt + 15) >> 4;
    for (int tile = 0; tile < ntiles; ++tile) {
        int ge0 = rp0 + tile * 16;
        __syncthreads();
        if (t < 16) sendS[t] = send_s[ge0 + t];
        else if (t < 32) {
            int e = ge0 + (t - 16);
            int nl = 3;
            if (e < rowptr[n0 + 1]) nl = 0;
            else if (e < rowptr[n0 + 2]) nl = 1;
            else if (e < rowptr[n0 + 3]) nl = 2;
            nlS[t - 16] = nl;
        }
        // poly -> h1 (bf16); thread owns column c, half the rows
        const float2* ap = (const float2*)attr_s + (size_t)ge0 * 12 + rh * 96;
        for (int r = 0; r < 96; ++r) {
            float2 abv = ap[r];
            float a = abv.x, b = abv.y;
            float aa = a * a, ab = a * b, bb = b * b;
            float v = b1v + a * w_a + b * w_b + aa * w_aa + ab * w_ab + bb * w_bb
                    + aa * a * w_aaa + aa * b * w_aab + bb * a * w_abb + bb * b * w_bbb;
            A_lds[(rh * 96 + r) * 136 + c] = (__bf16)gelu_f(v);
        }
        __syncthreads();
        int rb = w * 48;                       // wave-owned rows [rb, rb+48)
        f32x4 acc[3][8];
        #pragma unroll
        for (int mt = 0; mt < 3; ++mt)
            #pragma unroll
            for (int nt = 0; nt < 8; ++nt) acc[mt][nt] = (f32x4){0.f, 0.f, 0.f, 0.f};
        // GEMM1: kb_pre = h1 @ Wsp2
        #pragma unroll
        for (int ks = 0; ks < 4; ++ks) {
            bf16x8 bfr[8];
            #pragma unroll
            for (int nt = 0; nt < 8; ++nt)
                bfr[nt] = *(const bf16x8*)(W2T + (nt * 16 + l15) * 128 + ks * 32 + quad * 8);
            #pragma unroll
            for (int mt = 0; mt < 3; ++mt) {
                bf16x8 af = *(const bf16x8*)(A_lds + (rb + mt * 16 + l15) * 136 + ks * 32 + quad * 8);
                #pragma unroll
                for (int nt = 0; nt < 8; ++nt)
                    acc[mt][nt] = __builtin_amdgcn_mfma_f32_16x16x32_bf16(af, bfr[nt], acc[mt][nt], 0, 0, 0);
            }
        }
        // bias + gelu -> kb, write back into own rows (wave-local)
        #pragma unroll
        for (int mt = 0; mt < 3; ++mt)
            #pragma unroll
            for (int nt = 0; nt < 8; ++nt)
                #pragma unroll
                for (int rg = 0; rg < 4; ++rg) {
                    int row = rb + mt * 16 + quad * 4 + rg;
                    A_lds[row * 136 + nt * 16 + l15] = (__bf16)gelu_f(acc[mt][nt][rg] + b2v[nt]);
                }
        #pragma unroll
        for (int mt = 0; mt < 3; ++mt)
            #pragma unroll
            for (int nt = 0; nt < 8; ++nt) acc[mt][nt] = (f32x4){0.f, 0.f, 0.f, 0.f};
        // GEMM2: k = kb @ Wk[l]
        #pragma unroll
        for (int ks = 0; ks < 4; ++ks) {
            bf16x8 bfr[8];
            #pragma unroll
            for (int nt = 0; nt < 8; ++nt)
                bfr[nt] = *(const bf16x8*)(WkTl + (nt * 16 + l15) * 128 + ks * 32 + quad * 8);
            #pragma unroll
            for (int mt = 0; mt < 3; ++mt) {
                bf16x8 af = *(const bf16x8*)(A_lds + (rb + mt * 16 + l15) * 136 + ks * 32 + quad * 8);
                #pragma unroll
                for (int nt = 0; nt < 8; ++nt)
                    acc[mt][nt] = __builtin_amdgcn_mfma_f32_16x16x32_bf16(af, bfr[nt], acc[mt][nt], 0, 0, 0);
            }
        }
        // epilogue: msg = h_bf[send] * k ; ds_add into per-block agg
        int ecnt = cnt - tile * 16;
        if (ecnt > 16) ecnt = 16;
        #pragma unroll
        for (int mt = 0; mt < 3; ++mt) {
            #pragma unroll
            for (int rg = 0; rg < 4; ++rg) {
                int row = rb + mt * 16 + quad * 4 + rg;
                int el = row / 12;
                if (el < ecnt) {
                    int g = row - el * 12;
                    const __bf16* hb = h_bf + ((size_t)sendS[el] * 12 + g) * 128;
                    float* as = aggS + (nlS[el] * 12 + g) * 128;
                    #pragma unroll
                    for (int nt = 0; nt < 8; ++nt) {
                        int cc = nt * 16 + l15;
                        atomicAdd(&as[cc], acc[mt][nt][rg] * (float)hb[cc]);
                    }
                }
            }
        }
    }
    __syncthreads();
    for (int i = t; i < NPB * 1536; i += 256)
        agg[(size_t)n0 * 1536 + i] = aggS[i];
}

// ---------------- per-layer per-node: conv + LN + MLP + residual + readout ----------------
__global__ __launch_bounds__(128) void k_node(
    const float* __restrict__ agg, const float* __restrict__ fk,
    const float* __restrict__ bconv, const float* __restrict__ ln_g,
    const float* __restrict__ ln_b,
    const float* __restrict__ W1, const float* __restrict__ b1,
    const float* __restrict__ W2, const float* __restrict__ b2,
    const float* __restrict__ Wro, const float* __restrict__ bro,
    __bf16* __restrict__ h_bf, float* __restrict__ readout) {
    __shared__ __align__(16) float A[12 * 128];
    __shared__ __align__(16) float H[12 * 128];
    __shared__ __align__(16) float HIDS[12 * 512];
    __shared__ float red[12][2][2];
    int n = blockIdx.x, t = threadIdx.x;
    int lane = t & 63, wid = t >> 6;
    for (int i = t; i < 1536; i += 128) A[i] = agg[(size_t)n * 1536 + i];
    __syncthreads();
    float x2v[12];
    float bcv = bconv[t];
    #pragma unroll
    for (int p = 0; p < 12; ++p) {
        float acc = 0.f;
        #pragma unroll
        for (int o = 0; o < 12; ++o) acc += A[o * 128 + t] * fk[(p * 12 + o) * 128 + t];
        x2v[p] = acc * (1.0f / 12.0f) + bcv;
    }
    #pragma unroll
    for (int p = 0; p < 12; ++p) {
        float s = x2v[p], s2 = x2v[p] * x2v[p];
        for (int off = 32; off > 0; off >>= 1) {
            s += __shfl_down(s, off);
            s2 += __shfl_down(s2, off);
        }
        if (lane == 0) { red[p][wid][0] = s; red[p][wid][1] = s2; }
    }
    __syncthreads();
    float gv = ln_g[t], bv = ln_b[t];
    #pragma unroll
    for (int p = 0; p < 12; ++p) {
        float mu = (red[p][0][0] + red[p][1][0]) * (1.0f / 128.0f);
        float var = (red[p][0][1] + red[p][1][1]) * (1.0f / 128.0f) - mu * mu;
        H[p * 128 + t] = (x2v[p] - mu) * rsqrtf(var + 1e-5f) * gv + bv;
    }
    __syncthreads();
    for (int q = 0; q < 4; ++q) {
        int j = t + q * 128;
        float acc[12];
        float bj = b1[j];
        #pragma unroll
        for (int p = 0; p < 12; ++p) acc[p] = bj;
        for (int k = 0; k < 128; k += 4) {
            float wv0 = W1[(k+0) * 512 + j], wv1 = W1[(k+1) * 512 + j];
            float wv2 = W1[(k+2) * 512 + j], wv3 = W1[(k+3) * 512 + j];
            #pragma unroll
            for (int p = 0; p < 12; ++p) {
                float4 hv = *(const float4*)&H[p * 128 + k];
                acc[p] += hv.x * wv0 + hv.y * wv1 + hv.z * wv2 + hv.w * wv3;
            }
        }
        #pragma unroll
        for (int p = 0; p < 12; ++p) HIDS[p * 512 + j] = gelu_f(acc[p]);
    }
    __syncthreads();
    float acc2[12];
    float b2v = b2[t];
    #pragma unroll
    for (int p = 0; p < 12; ++p) acc2[p] = b2v;
    for (int k = 0; k < 512; k += 4) {
        float wv0 = W2[(k+0) * 128 + t], wv1 = W2[(k+1) * 128 + t];
        float wv2 = W2[(k+2) * 128 + t], wv3 = W2[(k+3) * 128 + t];
        #pragma unroll
        for (int p = 0; p < 12; ++p) {
            float4 hv = *(const float4*)&HIDS[p * 512 + k];
            acc2[p] += hv.x * wv0 + hv.y * wv1 + hv.z * wv2 + hv.w * wv3;
        }
    }
    #pragma unroll
    for (int p = 0; p < 12; ++p) {
        size_t hi = (size_t)n * 1536 + p * 128 + t;
        float hv = (float)h_bf[hi] + acc2[p];
        h_bf[hi] = (__bf16)hv;
        H[p * 128 + t] = hv;
    }
    __syncthreads();
    if (t < 108) {
        int p = t / 9, j = t % 9;
        float acc = 0.f;
        for (int cc = 0; cc < 128; ++cc) acc += H[p * 128 + cc] * Wro[cc * 9 + j];
        readout[((size_t)n * 12 + p) * 9 + j] += (acc + bro[j]) * (1.0f / 3.0f);
    }
}

// ---------------- final pooling ----------------
__global__ __launch_bounds__(128) void k_out(
    const float* __restrict__ readout, const float* __restrict__ node_grid,
    const int* __restrict__ batch, float* __restrict__ out) {
    int n = blockIdx.x * 128 + threadIdx.x;
    if (n >= N_NODES) return;
    int b = batch[n];
    const float* ro = readout + (size_t)n * 108;
    float ss[8] = {0, 0, 0, 0, 0, 0, 0, 0};
    float v0 = 0.f, v1 = 0.f, v2 = 0.f;
    for (int p = 0; p < 12; ++p) {
        #pragma unroll
        for (int j = 0; j < 8; ++j) ss[j] += ro[p * 9 + j];
        float rv = ro[p * 9 + 8];
        v0 += rv * node_grid[n * 36 + p * 3 + 0];
        v1 += rv * node_grid[n * 36 + p * 3 + 1];
        v2 += rv * node_grid[n * 36 + p * 3 + 2];
    }
    #pragma unroll
    for (int j = 0; j < 8; ++j) atomicAdd(&out[b * 8 + j], ss[j] * (1.0f / 12.0f));
    atomicAdd(&out[512 + b * 3 + 0], v0 * (1.0f / 12.0f));
    atomicAdd(&out[512 + b * 3 + 1], v1 * (1.0f / 12.0f));
    atomicAdd(&out[512 + b * 3 + 2], v2 * (1.0f / 12.0f));
}

extern "C" void kernel_launch(void* const* d_in, const int* in_sizes, int n_in,
                              void* d_out, int out_size, void* d_ws, size_t ws_size,
                              hipStream_t stream) {
    const float* x    = (const float*)d_in[0];
    const float* vec  = (const float*)d_in[1];
    const float* pos  = (const float*)d_in[2];
    const float* Q    = (const float*)d_in[3];
    const float* Wsp1 = (const float*)d_in[4];
    const float* bsp1 = (const float*)d_in[5];
    const float* Wsp2 = (const float*)d_in[6];
    const float* bsp2 = (const float*)d_in[7];
    const float* Wsh1 = (const float*)d_in[8];
    const float* bsh1 = (const float*)d_in[9];
    const float* Wsh2 = (const float*)d_in[10];
    const float* bsh2 = (const float*)d_in[11];
    const float* Wemb = (const float*)d_in[12];
    const float* Wk   = (const float*)d_in[13];
    const float* Wfk  = (const float*)d_in[14];
    const float* bconv= (const float*)d_in[15];
    const float* ln_g = (const float*)d_in[16];
    const float* ln_b = (const float*)d_in[17];
    const float* W1   = (const float*)d_in[18];
    const float* b1   = (const float*)d_in[19];
    const float* W2   = (const float*)d_in[20];
    const float* b2   = (const float*)d_in[21];
    const float* Wro  = (const float*)d_in[22];
    const float* bro  = (const float*)d_in[23];
    const int* ei     = (const int*)d_in[24];
    const int* batch  = (const int*)d_in[25];
    const int* send = ei;
    const int* recv = ei + N_EDGES;

    // workspace layout (float slots) — total 21,362,896 floats = 85.5 MB
    float* ws     = (float*)d_ws;
    float* grid0  = ws;                        // 64
    float* grid   = ws + 64;                   // 2304
    float* fk     = ws + 2368;                 // 55296
    float* ng     = ws + 57664;                // 288000
    float* ro     = ws + 345664;               // 864000
    float* attr_s = ws + 1209664;              // 1536384 ((64000+16)*24)
    float* agg    = ws + 2746048;              // 12288000
    __bf16* WT    = (__bf16*)(ws + 15034048);  // 65536 bf16 = 32768 floats
    __bf16* h_bf  = (__bf16*)(ws + 15066816);  // 12288000 bf16 = 6144000 floats
    int*   ibase  = (int*)(ws + 21210816);
    int* deg    = ibase;            // 8000
    int* cursor = ibase + 8000;     // 8000
    int* rowptr = ibase + 16000;    // 8064
    int* perm   = ibase + 24064;    // 64000
    int* send_s = ibase + 88064;    // 64016
    const size_t NEED = 21362896ull * 4ull;
    if (ws_size < NEED) return;

    hipMemsetAsync(d_out, 0, sizeof(float) * (size_t)out_size, stream);
    hipMemsetAsync(ro, 0, sizeof(float) * 864000, stream);
    hipMemsetAsync(deg, 0, sizeof(int) * 8000, stream);

    k_grid<<<1, 256, 0, stream>>>(Q, grid0, grid);
    k_kbsh<<<144, 128, 0, stream>>>(grid0, Wsh1, bsh1, Wsh2, bsh2, Wfk, fk);
    k_embed<<<N_NODES, 128, 0, stream>>>(x, vec, batch, grid, Wemb, ng, h_bf);
    k_deg<<<250, 256, 0, stream>>>(recv, deg);
    k_scan<<<1, 1024, 0, stream>>>(deg, rowptr, cursor);
    k_fill<<<250, 256, 0, stream>>>(recv, cursor, perm);
    k_attr_sorted<<<((N_EDGES + 16) * 12 + 255) / 256, 256, 0, stream>>>(
        pos, ng, send, recv, perm, attr_s, send_s);
    k_prepw<<<256, 256, 0, stream>>>(Wsp2, Wk, WT);

    for (int l = 0; l < 3; ++l) {
        k_edge_csr<<<N_NODES / NPB, 256, 0, stream>>>(attr_s, send_s, rowptr,
            WT, WT + (1 + l) * 16384, Wsp1, bsp1, bsp2, h_bf, agg);
        k_node<<<N_NODES, 128, 0, stream>>>(agg, fk + l * 18432, bconv + l * 128,
            ln_g + l * 128, ln_b + l * 128, W1 + l * 65536, b1 + l * 512,
            W2 + l * 65536, b2 + l * 128, Wro + l * 1152, bro + l * 9, h_bf, ro);
    }
    k_out<<<(N_NODES + 127) / 128, 128, 0, stream>>>(ro, ng, batch, (float*)d_out);
}

// Round 5
// 4572.921 us; speedup vs baseline: 1.2522x; 1.2522x over previous
//
#include <hip/hip_runtime.h>
#include <hip/hip_bf16.h>

#define N_NODES 8000
#define N_EDGES 64000
#define NBATCH  64
#define NGRID   12
#define HIDC    128
#define NPB     4        // recv-nodes per edge-block
#define MNPB    4        // nodes per mlp-block

typedef __bf16 bf16x8 __attribute__((ext_vector_type(8)));
typedef float  f32x4  __attribute__((ext_vector_type(4)));

__device__ __forceinline__ float gelu_f(float x) {
    return 0.5f * x * (1.0f + erff(x * 0.70710678118654752440f));
}

// ---------------- grid0 + per-batch rotated grids ----------------
__global__ void k_grid(const float* __restrict__ Q, float* __restrict__ grid0,
                       float* __restrict__ grid) {
    int t = threadIdx.x;
    __shared__ float g0[12][3];
    if (t < 12) {
        float fi = (float)t;
        float theta = 6.28318530717958647692f * fi / 1.61803398874989484820f;
        float z = 1.0f - (2.0f * fi + 1.0f) / 12.0f;
        float r = sqrtf(fmaxf(1.0f - z * z, 0.0f));
        g0[t][0] = r * cosf(theta);
        g0[t][1] = r * sinf(theta);
        g0[t][2] = z;
        grid0[t * 3 + 0] = g0[t][0];
        grid0[t * 3 + 1] = g0[t][1];
        grid0[t * 3 + 2] = g0[t][2];
    }
    __syncthreads();
    for (int idx = t; idx < NBATCH * 12 * 3; idx += blockDim.x) {
        int b = idx / 36, rmd = idx % 36, n = rmd / 3, i = rmd % 3;
        float acc = 0.f;
        #pragma unroll
        for (int j = 0; j < 3; ++j) acc += Q[b * 9 + i * 3 + j] * g0[n][j];
        grid[idx] = acc;
    }
}

// ---------------- kb_sh -> fk  (3,12,12,128) ----------------
__global__ __launch_bounds__(128) void k_kbsh(
    const float* __restrict__ grid0,
    const float* __restrict__ Wsh1, const float* __restrict__ bsh1,
    const float* __restrict__ Wsh2, const float* __restrict__ bsh2,
    const float* __restrict__ Wfk, float* __restrict__ fk) {
    int row = blockIdx.x;            // p*12+o
    int p = row / 12, o = row % 12, t = threadIdx.x;
    float tt = grid0[p*3]*grid0[o*3] + grid0[p*3+1]*grid0[o*3+1] + grid0[p*3+2]*grid0[o*3+2];
    float p1 = tt, p2 = tt * tt, p3 = p2 * tt;
    float h1 = gelu_f(p1 * Wsh1[t] + p2 * Wsh1[128 + t] + p3 * Wsh1[256 + t] + bsh1[t]);
    __shared__ float h1S[128];
    __shared__ float h2S[128];
    h1S[t] = h1;
    __syncthreads();
    float acc = bsh2[t];
    #pragma unroll 8
    for (int k = 0; k < 128; ++k) acc += h1S[k] * Wsh2[k * 128 + t];
    h2S[t] = gelu_f(acc);
    __syncthreads();
    for (int l = 0; l < 3; ++l) {
        float a = 0.f;
        #pragma unroll 8
        for (int k = 0; k < 128; ++k) a += h2S[k] * Wfk[l * 16384 + k * 128 + t];
        fk[l * 18432 + row * 128 + t] = a;
    }
}

// ---------------- node_grid + h0 = f @ Wemb (h stored bf16) ----------------
__global__ __launch_bounds__(128) void k_embed(
    const float* __restrict__ x, const float* __restrict__ vec,
    const int* __restrict__ batch, const float* __restrict__ grid,
    const float* __restrict__ Wemb, float* __restrict__ node_grid,
    __bf16* __restrict__ h_bf) {
    __shared__ float WembS[18 * 128];
    __shared__ float ngS[36];
    __shared__ float xS[16];
    __shared__ float vS[6];
    int n = blockIdx.x, t = threadIdx.x;
    for (int i = t; i < 18 * 128; i += 128) WembS[i] = Wemb[i];
    int b = batch[n];
    if (t < 36) { float g = grid[b * 36 + t]; ngS[t] = g; node_grid[n * 36 + t] = g; }
    if (t < 16) xS[t] = x[n * 16 + t];
    if (t >= 16 && t < 22) vS[t - 16] = vec[n * 6 + (t - 16)];
    __syncthreads();
    for (int g = 0; g < NGRID; ++g) {
        float g0 = ngS[g*3], g1 = ngS[g*3+1], g2 = ngS[g*3+2];
        float xv0 = vS[0]*g0 + vS[1]*g1 + vS[2]*g2;
        float xv1 = vS[3]*g0 + vS[4]*g1 + vS[5]*g2;
        float acc = xv0 * WembS[16*128 + t] + xv1 * WembS[17*128 + t];
        #pragma unroll
        for (int j = 0; j < 16; ++j) acc += xS[j] * WembS[j*128 + t];
        h_bf[((size_t)n * NGRID + g) * HIDC + t] = (__bf16)acc;
    }
}

// ---------------- CSR build ----------------
__global__ __launch_bounds__(256) void k_deg(const int* __restrict__ recv,
                                             int* __restrict__ deg) {
    int e = blockIdx.x * 256 + threadIdx.x;
    if (e < N_EDGES) atomicAdd(&deg[recv[e]], 1);
}

__global__ __launch_bounds__(1024) void k_scan(const int* __restrict__ deg,
                                               int* __restrict__ rowptr,
                                               int* __restrict__ cursor) {
    __shared__ int part[1024];
    int t = threadIdx.x;
    int base = t * 8;
    int local[8];
    int s = 0;
    #pragma unroll
    for (int j = 0; j < 8; ++j) {
        int idx = base + j;
        int v = (idx < N_NODES) ? deg[idx] : 0;
        local[j] = s;
        s += v;
    }
    part[t] = s;
    __syncthreads();
    for (int off = 1; off < 1024; off <<= 1) {
        int v = (t >= off) ? part[t - off] : 0;
        __syncthreads();
        part[t] += v;
        __syncthreads();
    }
    int excl = (t == 0) ? 0 : part[t - 1];
    #pragma unroll
    for (int j = 0; j < 8; ++j) {
        int idx = base + j;
        if (idx < N_NODES) {
            int v = excl + local[j];
            rowptr[idx] = v;
            cursor[idx] = v;
        }
    }
    if (t == 1023) rowptr[N_NODES] = part[1023];
}

__global__ __launch_bounds__(256) void k_fill(const int* __restrict__ recv,
                                              int* __restrict__ cursor,
                                              int* __restrict__ perm) {
    int e = blockIdx.x * 256 + threadIdx.x;
    if (e < N_EDGES) {
        int r = recv[e];
        int p = atomicAdd(&cursor[r], 1);
        perm[p] = e;
    }
}

// ---------------- per-(sorted-edge,grid) invariants + sorted send ----------------
__global__ __launch_bounds__(256) void k_attr_sorted(
    const float* __restrict__ pos, const float* __restrict__ ng,
    const int* __restrict__ send, const int* __restrict__ recv,
    const int* __restrict__ perm,
    float* __restrict__ attr_s, int* __restrict__ send_s) {
    int idx = blockIdx.x * 256 + threadIdx.x;
    if (idx >= (N_EDGES + 16) * 12) return;
    int i = idx / 12, g = idx % 12;
    if (i < N_EDGES) {
        int e = perm[i];
        int s = send[e], r = recv[e];
        float rx = pos[s*3+0] - pos[r*3+0];
        float ry = pos[s*3+1] - pos[r*3+1];
        float rz = pos[s*3+2] - pos[r*3+2];
        const float* gr = ng + ((size_t)r * 12 + g) * 3;
        float g0 = gr[0], g1 = gr[1], g2 = gr[2];
        float iv1 = rx*g0 + ry*g1 + rz*g2;
        float wx = rx - iv1*g0, wy = ry - iv1*g1, wz = rz - iv1*g2;
        attr_s[(size_t)idx * 2 + 0] = iv1;
        attr_s[(size_t)idx * 2 + 1] = sqrtf(wx*wx + wy*wy + wz*wz);
        if (g == 0) send_s[i] = s;
    } else {
        attr_s[(size_t)idx * 2 + 0] = 0.f;
        attr_s[(size_t)idx * 2 + 1] = 0.f;
        if (g == 0) send_s[i] = 0;
    }
}

// ---- transposed bf16 weights: [Wsp2T | WkT l=0..2 | W1T l=0..2 | W2T l=0..2] ----
__global__ __launch_bounds__(256) void k_prepw2(
    const float* __restrict__ Wsp2, const float* __restrict__ Wk,
    const float* __restrict__ W1, const float* __restrict__ W2,
    __bf16* __restrict__ WT) {
    int i = blockIdx.x * 256 + threadIdx.x;
    if (i >= 7 * 65536) return;       // 65536 (Wsp2T+WkT) + 3*65536 (W1T) + 3*65536 (W2T)
    float v;
    if (i < 65536) {
        int buf = i >> 14, r = i & 16383;
        int n = r >> 7, k = r & 127;
        v = (buf == 0) ? Wsp2[k * 128 + n] : Wk[(buf - 1) * 16384 + k * 128 + n];
    } else {
        int i2 = i - 65536;
        int l = i2 >> 16, r = i2 & 65535;
        if (l < 3) {                  // W1T[l]: [512 n x 128 k]
            int n = r >> 7, k = r & 127;
            v = W1[l * 65536 + k * 512 + n];
        } else {                      // W2T[l]: [128 n x 512 k]
            int l2 = l - 3;
            int n = r >> 9, k = r & 511;
            v = W2[l2 * 65536 + k * 128 + n];
        }
    }
    WT[i] = (__bf16)v;
}

// ---------------- per-layer fused edge kernel v2 ----------------
// 8-edge tiles (96 rows). Waves N-split: wave w owns output cols [32w,32w+32);
// B-fragments for BOTH GEMMs persistent in registers (loaded once).
// Accumulators streamed per 16-row m-tile (8 VGPRs live) -> no spills.
// Epilogue: thread-per-channel, coalesced h_bf reads, ds_add into aggS.
__global__ __launch_bounds__(256) void k_edge2(
    const float* __restrict__ attr_s, const int* __restrict__ send_s,
    const int* __restrict__ rowptr,
    const __bf16* __restrict__ W2T, const __bf16* __restrict__ WkTl,
    const float* __restrict__ Wsp1, const float* __restrict__ bsp1,
    const float* __restrict__ bsp2,
    const __bf16* __restrict__ h_bf, float* __restrict__ agg) {
    __shared__ __align__(16) __bf16 H1[96 * 136];
    __shared__ __align__(16) __bf16 KB[96 * 136];
    __shared__ float aggS[NPB * 1536];
    __shared__ int sendS[8], nlS[8];
    int t = threadIdx.x;
    int lane = t & 63, w = t >> 6, l15 = lane & 15, quad = lane >> 4;
    int c = t & 127, rh = t >> 7;
    int n0 = blockIdx.x * NPB;
    int rp0 = rowptr[n0];
    int rp1 = rowptr[n0 + 1], rp2 = rowptr[n0 + 2], rp3 = rowptr[n0 + 3];
    int cnt = rowptr[n0 + NPB] - rp0;

    for (int i = t; i < NPB * 1536; i += 256) aggS[i] = 0.f;

    // persistent B fragments (both GEMMs), cols w*32 + j*16 + l15
    bf16x8 Bw1[2][4], Bw2[2][4];
    #pragma unroll
    for (int j = 0; j < 2; ++j)
        #pragma unroll
        for (int ks = 0; ks < 4; ++ks) {
            int col = w * 32 + j * 16 + l15;
            Bw1[j][ks] = *(const bf16x8*)(W2T + (size_t)col * 128 + ks * 32 + quad * 8);
            Bw2[j][ks] = *(const bf16x8*)(WkTl + (size_t)col * 128 + ks * 32 + quad * 8);
        }
    float b2v[2] = { bsp2[w * 32 + l15], bsp2[w * 32 + 16 + l15] };

    // per-column poly weights (combined poly_features duplicates)
    float w_a, w_b, w_aa, w_ab, w_bb, w_aaa, w_aab, w_abb, w_bbb, b1v;
    {
        float w1[14];
        #pragma unroll
        for (int j = 0; j < 14; ++j) w1[j] = Wsp1[j * 128 + c];
        w_a = w1[0]; w_b = w1[1];
        w_aa = w1[2]; w_ab = w1[3] + w1[4]; w_bb = w1[5];
        w_aaa = w1[6]; w_aab = w1[7] + w1[8] + w1[10];
        w_abb = w1[9] + w1[11] + w1[12]; w_bbb = w1[13];
        b1v = bsp1[c];
    }

    int ntiles = (cnt + 7) >> 3;
    for (int tile = 0; tile < ntiles; ++tile) {
        int ge0 = rp0 + tile * 8;
        if (t < 8) sendS[t] = send_s[ge0 + t];
        else if (t < 16) {
            int e = ge0 + (t - 8);
            nlS[t - 8] = (e < rp1) ? 0 : (e < rp2) ? 1 : (e < rp3) ? 2 : 3;
        }
        // poly -> h1 bf16; thread owns col c, rows rh*48..rh*48+48
        const float2* ap = (const float2*)attr_s + (size_t)ge0 * 12 + rh * 48;
        #pragma unroll 6
        for (int i = 0; i < 48; ++i) {
            float2 abv = ap[i];
            float a = abv.x, b = abv.y;
            float aa = a * a, ab = a * b, bb = b * b;
            float v = b1v + a * w_a + b * w_b + aa * w_aa + ab * w_ab + bb * w_bb
                    + aa * a * w_aaa + aa * b * w_aab + bb * a * w_abb + bb * b * w_bbb;
            H1[(rh * 48 + i) * 136 + c] = (__bf16)gelu_f(v);
        }
        __syncthreads();
        // GEMM1: KB = gelu(H1 @ Wsp2 + b), streamed acc
        #pragma unroll
        for (int mt = 0; mt < 6; ++mt) {
            bf16x8 af[4];
            #pragma unroll
            for (int ks = 0; ks < 4; ++ks)
                af[ks] = *(const bf16x8*)(H1 + (mt * 16 + l15) * 136 + ks * 32 + quad * 8);
            f32x4 a0 = {0.f,0.f,0.f,0.f}, a1 = {0.f,0.f,0.f,0.f};
            #pragma unroll
            for (int ks = 0; ks < 4; ++ks) {
                a0 = __builtin_amdgcn_mfma_f32_16x16x32_bf16(af[ks], Bw1[0][ks], a0, 0, 0, 0);
                a1 = __builtin_amdgcn_mfma_f32_16x16x32_bf16(af[ks], Bw1[1][ks], a1, 0, 0, 0);
            }
            #pragma unroll
            for (int rg = 0; rg < 4; ++rg) {
                int row = mt * 16 + quad * 4 + rg;
                KB[row * 136 + w * 32 + l15]      = (__bf16)gelu_f(a0[rg] + b2v[0]);
                KB[row * 136 + w * 32 + 16 + l15] = (__bf16)gelu_f(a1[rg] + b2v[1]);
            }
        }
        __syncthreads();
        // GEMM2: k = KB @ Wk[l]  -> into H1 (bf16)
        #pragma unroll
        for (int mt = 0; mt < 6; ++mt) {
            bf16x8 af[4];
            #pragma unroll
            for (int ks = 0; ks < 4; ++ks)
                af[ks] = *(const bf16x8*)(KB + (mt * 16 + l15) * 136 + ks * 32 + quad * 8);
            f32x4 a0 = {0.f,0.f,0.f,0.f}, a1 = {0.f,0.f,0.f,0.f};
            #pragma unroll
            for (int ks = 0; ks < 4; ++ks) {
                a0 = __builtin_amdgcn_mfma_f32_16x16x32_bf16(af[ks], Bw2[0][ks], a0, 0, 0, 0);
                a1 = __builtin_amdgcn_mfma_f32_16x16x32_bf16(af[ks], Bw2[1][ks], a1, 0, 0, 0);
            }
            #pragma unroll
            for (int rg = 0; rg < 4; ++rg) {
                int row = mt * 16 + quad * 4 + rg;
                H1[row * 136 + w * 32 + l15]      = (__bf16)a0[rg];
                H1[row * 136 + w * 32 + 16 + l15] = (__bf16)a1[rg];
            }
        }
        __syncthreads();
        // epilogue: coalesced h gather, ds_add into aggS
        int ecnt = cnt - tile * 8;
        if (ecnt > 8) ecnt = 8;
        #pragma unroll
        for (int i = 0; i < 48; ++i) {
            int el = rh * 4 + i / 12;        // i static -> folds
            int g  = i % 12;
            if (el < ecnt) {
                float hv = (float)h_bf[((size_t)sendS[el] * 12 + g) * 128 + c];
                float kv = (float)H1[(rh * 48 + i) * 136 + c];
                atomicAdd(&aggS[(nlS[el] * 12 + g) * 128 + c], hv * kv);
            }
        }
        __syncthreads();
    }
    for (int i = t; i < NPB * 1536; i += 256)
        agg[(size_t)n0 * 1536 + i] = aggS[i];
}

// ---------------- per-layer fused node kernel: conv + LN + MFMA MLP + readout ----------------
__global__ __launch_bounds__(256) void k_mlp(
    const float* __restrict__ agg, const float* __restrict__ fkl,
    const float* __restrict__ bconv, const float* __restrict__ ln_g,
    const float* __restrict__ ln_b,
    const __bf16* __restrict__ W1T, const float* __restrict__ b1,
    const __bf16* __restrict__ W2T2, const float* __restrict__ b2,
    const float* __restrict__ Wro, const float* __restrict__ bro,
    __bf16* __restrict__ h_bf, float* __restrict__ readout) {
    __shared__ __align__(16) __bf16 X[48 * 136];
    __shared__ __align__(16) __bf16 HID[48 * 520];
    __shared__ float redS[48][2];
    int t = threadIdx.x;
    int lane = t & 63, w = t >> 6, l15 = lane & 15, quad = lane >> 4;
    int c = t & 127, nh = t >> 7;
    int n0 = blockIdx.x * MNPB;
    // conv: x2[p,c] = sum_o agg[o,c]*fk[p,o,c]/12 + bconv[c]
    float bcv = bconv[c];
    #pragma unroll
    for (int nn = nh; nn < 4; nn += 2) {
        float a[12];
        #pragma unroll
        for (int o = 0; o < 12; ++o)
            a[o] = agg[((size_t)(n0 + nn) * 12 + o) * 128 + c];
        #pragma unroll
        for (int p = 0; p < 12; ++p) {
            float s = 0.f;
            #pragma unroll
            for (int o = 0; o < 12; ++o) s += a[o] * fkl[(p * 12 + o) * 128 + c];
            X[(nn * 12 + p) * 136 + c] = (__bf16)(s * (1.0f / 12.0f) + bcv);
        }
    }
    __syncthreads();
    // LN stats: wave w rows [w*12, w*12+12)
    for (int r = w * 12; r < w * 12 + 12; ++r) {
        float v0 = (float)X[r * 136 + lane];
        float v1 = (float)X[r * 136 + 64 + lane];
        float s = v0 + v1, s2 = v0 * v0 + v1 * v1;
        for (int off = 32; off > 0; off >>= 1) {
            s += __shfl_down(s, off);
            s2 += __shfl_down(s2, off);
        }
        if (lane == 0) {
            float mu = s * (1.0f / 128.0f);
            float var = s2 * (1.0f / 128.0f) - mu * mu;
            redS[r][0] = mu;
            redS[r][1] = rsqrtf(var + 1e-5f);
        }
    }
    __syncthreads();
    float gv = ln_g[c], bv = ln_b[c];
    #pragma unroll
    for (int nn = nh; nn < 4; nn += 2)
        #pragma unroll
        for (int p = 0; p < 12; ++p) {
            int r = nn * 12 + p;
            float v = (float)X[r * 136 + c];
            X[r * 136 + c] = (__bf16)((v - redS[r][0]) * redS[r][1] * gv + bv);
        }
    __syncthreads();
    // GEMM1: HID = gelu(X @ W1 + b1); wave w -> cols [128w, 128w+128)
    #pragma unroll
    for (int mt = 0; mt < 3; ++mt) {
        bf16x8 af[4];
        #pragma unroll
        for (int ks = 0; ks < 4; ++ks)
            af[ks] = *(const bf16x8*)(X + (mt * 16 + l15) * 136 + ks * 32 + quad * 8);
        #pragma unroll
        for (int nt = 0; nt < 8; ++nt) {
            int colf = w * 128 + nt * 16 + l15;
            f32x4 acc = {0.f,0.f,0.f,0.f};
            #pragma unroll
            for (int ks = 0; ks < 4; ++ks) {
                bf16x8 bf = *(const bf16x8*)(W1T + (size_t)colf * 128 + ks * 32 + quad * 8);
                acc = __builtin_amdgcn_mfma_f32_16x16x32_bf16(af[ks], bf, acc, 0, 0, 0);
            }
            float bj = b1[colf];
            #pragma unroll
            for (int rg = 0; rg < 4; ++rg) {
                int row = mt * 16 + quad * 4 + rg;
                HID[row * 520 + colf] = (__bf16)gelu_f(acc[rg] + bj);
            }
        }
    }
    __syncthreads();
    // GEMM2: out = HID @ W2 + b2 + residual; wave w -> cols [32w, 32w+32)
    #pragma unroll
    for (int mt = 0; mt < 3; ++mt) {
        f32x4 a0 = {0.f,0.f,0.f,0.f}, a1 = {0.f,0.f,0.f,0.f};
        #pragma unroll
        for (int ks = 0; ks < 16; ++ks) {
            bf16x8 af = *(const bf16x8*)(HID + (mt * 16 + l15) * 520 + ks * 32 + quad * 8);
            bf16x8 b0 = *(const bf16x8*)(W2T2 + (size_t)(w * 32 + l15) * 512 + ks * 32 + quad * 8);
            bf16x8 b1f = *(const bf16x8*)(W2T2 + (size_t)(w * 32 + 16 + l15) * 512 + ks * 32 + quad * 8);
            a0 = __builtin_amdgcn_mfma_f32_16x16x32_bf16(af, b0, a0, 0, 0, 0);
            a1 = __builtin_amdgcn_mfma_f32_16x16x32_bf16(af, b1f, a1, 0, 0, 0);
        }
        float bj0 = b2[w * 32 + l15], bj1 = b2[w * 32 + 16 + l15];
        #pragma unroll
        for (int rg = 0; rg < 4; ++rg) {
            int row = mt * 16 + quad * 4 + rg;
            int node = n0 + row / 12, p = row % 12;
            size_t hi = ((size_t)node * 12 + p) * 128;
            {
                int col = w * 32 + l15;
                float hv = (float)h_bf[hi + col] + a0[rg] + bj0;
                h_bf[hi + col] = (__bf16)hv;
                X[row * 136 + col] = (__bf16)hv;
            }
            {
                int col = w * 32 + 16 + l15;
                float hv = (float)h_bf[hi + col] + a1[rg] + bj1;
                h_bf[hi + col] = (__bf16)hv;
                X[row * 136 + col] = (__bf16)hv;
            }
        }
    }
    __syncthreads();
    // readout += (h @ Wro + bro)/3
    for (int idx = t; idx < 432; idx += 256) {
        int row = idx / 9, j = idx % 9;
        float s = 0.f;
        for (int cc = 0; cc < 128; ++cc) s += (float)X[row * 136 + cc] * Wro[cc * 9 + j];
        int node = n0 + row / 12, p = row % 12;
        readout[((size_t)node * 12 + p) * 9 + j] += (s + bro[j]) * (1.0f / 3.0f);
    }
}

// ---------------- final pooling ----------------
__global__ __launch_bounds__(128) void k_out(
    const float* __restrict__ readout, const float* __restrict__ node_grid,
    const int* __restrict__ batch, float* __restrict__ out) {
    int n = blockIdx.x * 128 + threadIdx.x;
    if (n >= N_NODES) return;
    int b = batch[n];
    const float* ro = readout + (size_t)n * 108;
    float ss[8] = {0, 0, 0, 0, 0, 0, 0, 0};
    float v0 = 0.f, v1 = 0.f, v2 = 0.f;
    for (int p = 0; p < 12; ++p) {
        #pragma unroll
        for (int j = 0; j < 8; ++j) ss[j] += ro[p * 9 + j];
        float rv = ro[p * 9 + 8];
        v0 += rv * node_grid[n * 36 + p * 3 + 0];
        v1 += rv * node_grid[n * 36 + p * 3 + 1];
        v2 += rv * node_grid[n * 36 + p * 3 + 2];
    }
    #pragma unroll
    for (int j = 0; j < 8; ++j) atomicAdd(&out[b * 8 + j], ss[j] * (1.0f / 12.0f));
    atomicAdd(&out[512 + b * 3 + 0], v0 * (1.0f / 12.0f));
    atomicAdd(&out[512 + b * 3 + 1], v1 * (1.0f / 12.0f));
    atomicAdd(&out[512 + b * 3 + 2], v2 * (1.0f / 12.0f));
}

extern "C" void kernel_launch(void* const* d_in, const int* in_sizes, int n_in,
                              void* d_out, int out_size, void* d_ws, size_t ws_size,
                              hipStream_t stream) {
    const float* x    = (const float*)d_in[0];
    const float* vec  = (const float*)d_in[1];
    const float* pos  = (const float*)d_in[2];
    const float* Q    = (const float*)d_in[3];
    const float* Wsp1 = (const float*)d_in[4];
    const float* bsp1 = (const float*)d_in[5];
    const float* Wsp2 = (const float*)d_in[6];
    const float* bsp2 = (const float*)d_in[7];
    const float* Wsh1 = (const float*)d_in[8];
    const float* bsh1 = (const float*)d_in[9];
    const float* Wsh2 = (const float*)d_in[10];
    const float* bsh2 = (const float*)d_in[11];
    const float* Wemb = (const float*)d_in[12];
    const float* Wk   = (const float*)d_in[13];
    const float* Wfk  = (const float*)d_in[14];
    const float* bconv= (const float*)d_in[15];
    const float* ln_g = (const float*)d_in[16];
    const float* ln_b = (const float*)d_in[17];
    const float* W1   = (const float*)d_in[18];
    const float* b1   = (const float*)d_in[19];
    const float* W2   = (const float*)d_in[20];
    const float* b2   = (const float*)d_in[21];
    const float* Wro  = (const float*)d_in[22];
    const float* bro  = (const float*)d_in[23];
    const int* ei     = (const int*)d_in[24];
    const int* batch  = (const int*)d_in[25];
    const int* send = ei;
    const int* recv = ei + N_EDGES;

    // workspace layout (float slots) — total 21,559,504 floats = 86.2 MB
    float* ws     = (float*)d_ws;
    float* grid0  = ws;                        // 64
    float* grid   = ws + 64;                   // 2304
    float* fk     = ws + 2368;                 // 55296
    float* ng     = ws + 57664;                // 288000
    float* ro     = ws + 345664;               // 864000
    float* attr_s = ws + 1209664;              // 1536384
    float* agg    = ws + 2746048;              // 12288000
    __bf16* WT    = (__bf16*)(ws + 15034048);  // 7*65536 bf16 = 229376 floats
    __bf16* h_bf  = (__bf16*)(ws + 15263424);  // 12288000 bf16 = 6144000 floats
    int*   ibase  = (int*)(ws + 21407424);
    int* deg    = ibase;            // 8000
    int* cursor = ibase + 8000;     // 8000
    int* rowptr = ibase + 16000;    // 8064
    int* perm   = ibase + 24064;    // 64000
    int* send_s = ibase + 88064;    // 64016
    const size_t NEED = 21559504ull * 4ull;
    if (ws_size < NEED) return;

    const __bf16* Wsp2T = WT;
    const __bf16* WkT   = WT + 16384;          // 3 x 16384
    const __bf16* W1T   = WT + 65536;          // 3 x 65536
    const __bf16* W2T   = WT + 65536 + 3 * 65536; // 3 x 65536

    hipMemsetAsync(d_out, 0, sizeof(float) * (size_t)out_size, stream);
    hipMemsetAsync(ro, 0, sizeof(float) * 864000, stream);
    hipMemsetAsync(deg, 0, sizeof(int) * 8000, stream);

    k_grid<<<1, 256, 0, stream>>>(Q, grid0, grid);
    k_kbsh<<<144, 128, 0, stream>>>(grid0, Wsh1, bsh1, Wsh2, bsh2, Wfk, fk);
    k_embed<<<N_NODES, 128, 0, stream>>>(x, vec, batch, grid, Wemb, ng, h_bf);
    k_deg<<<250, 256, 0, stream>>>(recv, deg);
    k_scan<<<1, 1024, 0, stream>>>(deg, rowptr, cursor);
    k_fill<<<250, 256, 0, stream>>>(recv, cursor, perm);
    k_attr_sorted<<<((N_EDGES + 16) * 12 + 255) / 256, 256, 0, stream>>>(
        pos, ng, send, recv, perm, attr_s, send_s);
    k_prepw2<<<(7 * 65536 + 255) / 256, 256, 0, stream>>>(Wsp2, Wk, W1, W2, WT);

    for (int l = 0; l < 3; ++l) {
        k_edge2<<<N_NODES / NPB, 256, 0, stream>>>(attr_s, send_s, rowptr,
            Wsp2T, WkT + l * 16384, Wsp1, bsp1, bsp2, h_bf, agg);
        k_mlp<<<N_NODES / MNPB, 256, 0, stream>>>(agg, fk + l * 18432,
            bconv + l * 128, ln_g + l * 128, ln_b + l * 128,
            W1T + l * 65536, b1 + l * 512, W2T + l * 65536, b2 + l * 128,
            Wro + l * 1152, bro + l * 9, h_bf, ro);
    }
    k_out<<<(N_NODES + 127) / 128, 128, 0, stream>>>(ro, ng, batch, (float*)d_out);
}

// Round 6
// 3105.243 us; speedup vs baseline: 1.8441x; 1.4726x over previous
//
#include <hip/hip_runtime.h>
#include <hip/hip_bf16.h>

#define N_NODES 8000
#define N_EDGES 64000
#define NBATCH  64
#define NGRID   12
#define HIDC    128
#define NPB     4        // recv-nodes per edge-block
#define MNPB    4        // nodes per mlp-block

typedef __bf16 bf16x8 __attribute__((ext_vector_type(8)));
typedef float  f32x4  __attribute__((ext_vector_type(4)));

// tanh-form GELU: |err| vs exact < ~1.5e-3, well under bf16 noise
__device__ __forceinline__ float gelu_f(float x) {
    float u = 0.7978845608f * x * (1.0f + 0.044715f * x * x);
    float e = __expf(2.0f * u);
    float t = 1.0f - 2.0f / (e + 1.0f);
    return 0.5f * x * (1.0f + t);
}

// ---------------- grid0 + per-batch rotated grids ----------------
__global__ void k_grid(const float* __restrict__ Q, float* __restrict__ grid0,
                       float* __restrict__ grid) {
    int t = threadIdx.x;
    __shared__ float g0[12][3];
    if (t < 12) {
        float fi = (float)t;
        float theta = 6.28318530717958647692f * fi / 1.61803398874989484820f;
        float z = 1.0f - (2.0f * fi + 1.0f) / 12.0f;
        float r = sqrtf(fmaxf(1.0f - z * z, 0.0f));
        g0[t][0] = r * cosf(theta);
        g0[t][1] = r * sinf(theta);
        g0[t][2] = z;
        grid0[t * 3 + 0] = g0[t][0];
        grid0[t * 3 + 1] = g0[t][1];
        grid0[t * 3 + 2] = g0[t][2];
    }
    __syncthreads();
    for (int idx = t; idx < NBATCH * 12 * 3; idx += blockDim.x) {
        int b = idx / 36, rmd = idx % 36, n = rmd / 3, i = rmd % 3;
        float acc = 0.f;
        #pragma unroll
        for (int j = 0; j < 3; ++j) acc += Q[b * 9 + i * 3 + j] * g0[n][j];
        grid[idx] = acc;
    }
}

// ---------------- kb_sh -> fk  (3,12,12,128) ----------------
__global__ __launch_bounds__(128) void k_kbsh(
    const float* __restrict__ grid0,
    const float* __restrict__ Wsh1, const float* __restrict__ bsh1,
    const float* __restrict__ Wsh2, const float* __restrict__ bsh2,
    const float* __restrict__ Wfk, float* __restrict__ fk) {
    int row = blockIdx.x;            // p*12+o
    int p = row / 12, o = row % 12, t = threadIdx.x;
    float tt = grid0[p*3]*grid0[o*3] + grid0[p*3+1]*grid0[o*3+1] + grid0[p*3+2]*grid0[o*3+2];
    float p1 = tt, p2 = tt * tt, p3 = p2 * tt;
    float h1 = gelu_f(p1 * Wsh1[t] + p2 * Wsh1[128 + t] + p3 * Wsh1[256 + t] + bsh1[t]);
    __shared__ float h1S[128];
    __shared__ float h2S[128];
    h1S[t] = h1;
    __syncthreads();
    float acc = bsh2[t];
    #pragma unroll 8
    for (int k = 0; k < 128; ++k) acc += h1S[k] * Wsh2[k * 128 + t];
    h2S[t] = gelu_f(acc);
    __syncthreads();
    for (int l = 0; l < 3; ++l) {
        float a = 0.f;
        #pragma unroll 8
        for (int k = 0; k < 128; ++k) a += h2S[k] * Wfk[l * 16384 + k * 128 + t];
        fk[l * 18432 + row * 128 + t] = a;
    }
}

// ---------------- node_grid + h0 = f @ Wemb (h stored bf16) ----------------
__global__ __launch_bounds__(128) void k_embed(
    const float* __restrict__ x, const float* __restrict__ vec,
    const int* __restrict__ batch, const float* __restrict__ grid,
    const float* __restrict__ Wemb, float* __restrict__ node_grid,
    __bf16* __restrict__ h_bf) {
    __shared__ float WembS[18 * 128];
    __shared__ float ngS[36];
    __shared__ float xS[16];
    __shared__ float vS[6];
    int n = blockIdx.x, t = threadIdx.x;
    for (int i = t; i < 18 * 128; i += 128) WembS[i] = Wemb[i];
    int b = batch[n];
    if (t < 36) { float g = grid[b * 36 + t]; ngS[t] = g; node_grid[n * 36 + t] = g; }
    if (t < 16) xS[t] = x[n * 16 + t];
    if (t >= 16 && t < 22) vS[t - 16] = vec[n * 6 + (t - 16)];
    __syncthreads();
    for (int g = 0; g < NGRID; ++g) {
        float g0 = ngS[g*3], g1 = ngS[g*3+1], g2 = ngS[g*3+2];
        float xv0 = vS[0]*g0 + vS[1]*g1 + vS[2]*g2;
        float xv1 = vS[3]*g0 + vS[4]*g1 + vS[5]*g2;
        float acc = xv0 * WembS[16*128 + t] + xv1 * WembS[17*128 + t];
        #pragma unroll
        for (int j = 0; j < 16; ++j) acc += xS[j] * WembS[j*128 + t];
        h_bf[((size_t)n * NGRID + g) * HIDC + t] = (__bf16)acc;
    }
}

// ---------------- CSR build ----------------
__global__ __launch_bounds__(256) void k_deg(const int* __restrict__ recv,
                                             int* __restrict__ deg) {
    int e = blockIdx.x * 256 + threadIdx.x;
    if (e < N_EDGES) atomicAdd(&deg[recv[e]], 1);
}

__global__ __launch_bounds__(1024) void k_scan(const int* __restrict__ deg,
                                               int* __restrict__ rowptr,
                                               int* __restrict__ cursor) {
    __shared__ int part[1024];
    int t = threadIdx.x;
    int base = t * 8;
    int local[8];
    int s = 0;
    #pragma unroll
    for (int j = 0; j < 8; ++j) {
        int idx = base + j;
        int v = (idx < N_NODES) ? deg[idx] : 0;
        local[j] = s;
        s += v;
    }
    part[t] = s;
    __syncthreads();
    for (int off = 1; off < 1024; off <<= 1) {
        int v = (t >= off) ? part[t - off] : 0;
        __syncthreads();
        part[t] += v;
        __syncthreads();
    }
    int excl = (t == 0) ? 0 : part[t - 1];
    #pragma unroll
    for (int j = 0; j < 8; ++j) {
        int idx = base + j;
        if (idx < N_NODES) {
            int v = excl + local[j];
            rowptr[idx] = v;
            cursor[idx] = v;
        }
    }
    if (t == 1023) rowptr[N_NODES] = part[1023];
}

__global__ __launch_bounds__(256) void k_fill(const int* __restrict__ recv,
                                              int* __restrict__ cursor,
                                              int* __restrict__ perm) {
    int e = blockIdx.x * 256 + threadIdx.x;
    if (e < N_EDGES) {
        int r = recv[e];
        int p = atomicAdd(&cursor[r], 1);
        perm[p] = e;
    }
}

// ---------------- per-(sorted-edge,grid) invariants + sorted send ----------------
__global__ __launch_bounds__(256) void k_attr_sorted(
    const float* __restrict__ pos, const float* __restrict__ ng,
    const int* __restrict__ send, const int* __restrict__ recv,
    const int* __restrict__ perm,
    float* __restrict__ attr_s, int* __restrict__ send_s) {
    int idx = blockIdx.x * 256 + threadIdx.x;
    if (idx >= (N_EDGES + 16) * 12) return;
    int i = idx / 12, g = idx % 12;
    if (i < N_EDGES) {
        int e = perm[i];
        int s = send[e], r = recv[e];
        float rx = pos[s*3+0] - pos[r*3+0];
        float ry = pos[s*3+1] - pos[r*3+1];
        float rz = pos[s*3+2] - pos[r*3+2];
        const float* gr = ng + ((size_t)r * 12 + g) * 3;
        float g0 = gr[0], g1 = gr[1], g2 = gr[2];
        float iv1 = rx*g0 + ry*g1 + rz*g2;
        float wx = rx - iv1*g0, wy = ry - iv1*g1, wz = rz - iv1*g2;
        attr_s[(size_t)idx * 2 + 0] = iv1;
        attr_s[(size_t)idx * 2 + 1] = sqrtf(wx*wx + wy*wy + wz*wz);
        if (g == 0) send_s[i] = s;
    } else {
        attr_s[(size_t)idx * 2 + 0] = 0.f;
        attr_s[(size_t)idx * 2 + 1] = 0.f;
        if (g == 0) send_s[i] = 0;
    }
}

// ---- transposed bf16 weights: [Wsp2T | WkT l=0..2 | W1T l=0..2 | W2T l=0..2] ----
__global__ __launch_bounds__(256) void k_prepw2(
    const float* __restrict__ Wsp2, const float* __restrict__ Wk,
    const float* __restrict__ W1, const float* __restrict__ W2,
    __bf16* __restrict__ WT) {
    int i = blockIdx.x * 256 + threadIdx.x;
    if (i >= 7 * 65536) return;
    float v;
    if (i < 65536) {
        int buf = i >> 14, r = i & 16383;
        int n = r >> 7, k = r & 127;
        v = (buf == 0) ? Wsp2[k * 128 + n] : Wk[(buf - 1) * 16384 + k * 128 + n];
    } else {
        int i2 = i - 65536;
        int l = i2 >> 16, r = i2 & 65535;
        if (l < 3) {                  // W1T[l]: [512 n x 128 k]
            int n = r >> 7, k = r & 127;
            v = W1[l * 65536 + k * 512 + n];
        } else {                      // W2T[l]: [128 n x 512 k]
            int l2 = l - 3;
            int n = r >> 9, k = r & 511;
            v = W2[l2 * 65536 + k * 128 + n];
        }
    }
    WT[i] = (__bf16)v;
}

// ---------------- per-layer fused edge kernel v3 ----------------
// 512 threads (8 waves), 4-edge tiles (48 rows). Wave w owns output cols
// [16w,16w+16) for both GEMMs; B-fragments persistent in registers.
// Single LDS tile H1 (reused in-place for KB); GEMM2 output stays in regs,
// epilogue straight from C-layout. aggS bank-swizzled by +16*g.
__global__ __launch_bounds__(512, 4) void k_edge3(
    const float* __restrict__ attr_s, const int* __restrict__ send_s,
    const int* __restrict__ rowptr,
    const __bf16* __restrict__ W2T, const __bf16* __restrict__ WkTl,
    const float* __restrict__ Wsp1, const float* __restrict__ bsp1,
    const float* __restrict__ bsp2,
    const __bf16* __restrict__ h_bf, float* __restrict__ agg) {
    __shared__ __align__(16) __bf16 H1[48 * 136];
    __shared__ float aggS[NPB * 1536];
    __shared__ int sendS[4], nlS[4];
    int t = threadIdx.x;
    int lane = t & 63, w = t >> 6, l15 = lane & 15, quad = lane >> 4;
    int c = t & 127, rh = t >> 7;          // rh in 0..3: poly row group
    int n0 = blockIdx.x * NPB;
    int rp0 = rowptr[n0];
    int rp1 = rowptr[n0 + 1], rp2 = rowptr[n0 + 2], rp3 = rowptr[n0 + 3];
    int cnt = rowptr[n0 + NPB] - rp0;

    for (int i = t; i < NPB * 1536; i += 512) aggS[i] = 0.f;

    // persistent B fragments: wave w cols 16w..16w+16
    bf16x8 Bw1[4], Bw2[4];
    #pragma unroll
    for (int ks = 0; ks < 4; ++ks) {
        int col = w * 16 + l15;
        Bw1[ks] = *(const bf16x8*)(W2T + (size_t)col * 128 + ks * 32 + quad * 8);
        Bw2[ks] = *(const bf16x8*)(WkTl + (size_t)col * 128 + ks * 32 + quad * 8);
    }
    float b2v = bsp2[w * 16 + l15];

    // per-column poly weights (combined poly_features duplicates)
    float w_a, w_b, w_aa, w_ab, w_bb, w_aaa, w_aab, w_abb, w_bbb, b1v;
    {
        float w1[14];
        #pragma unroll
        for (int j = 0; j < 14; ++j) w1[j] = Wsp1[j * 128 + c];
        w_a = w1[0]; w_b = w1[1];
        w_aa = w1[2]; w_ab = w1[3] + w1[4]; w_bb = w1[5];
        w_aaa = w1[6]; w_aab = w1[7] + w1[8] + w1[10];
        w_abb = w1[9] + w1[11] + w1[12]; w_bbb = w1[13];
        b1v = bsp1[c];
    }

    int ntiles = (cnt + 3) >> 2;
    for (int tile = 0; tile < ntiles; ++tile) {
        int ge0 = rp0 + tile * 4;
        __syncthreads();                         // A: H1 WAR vs prev GEMM2 reads
        if (t < 4) sendS[t] = send_s[ge0 + t];
        else if (t < 8) {
            int e = ge0 + (t - 4);
            nlS[t - 4] = (e < rp1) ? 0 : (e < rp2) ? 1 : (e < rp3) ? 2 : 3;
        }
        // poly -> h1 bf16; thread owns col c, rows rh*12..rh*12+12
        const float2* ap = (const float2*)attr_s + (size_t)ge0 * 12 + rh * 12;
        #pragma unroll
        for (int i = 0; i < 12; ++i) {
            float2 abv = ap[i];
            float a = abv.x, b = abv.y;
            float aa = a * a, ab = a * b, bb = b * b;
            float v = b1v + a * w_a + b * w_b + aa * w_aa + ab * w_ab + bb * w_bb
                    + aa * a * w_aaa + aa * b * w_aab + bb * a * w_abb + bb * b * w_bbb;
            H1[(rh * 12 + i) * 136 + c] = (__bf16)gelu_f(v);
        }
        __syncthreads();                         // B
        // GEMM1: acc1 = H1 @ Wsp2 (cols 16w..16w+16)
        f32x4 acc1[3];
        #pragma unroll
        for (int mt = 0; mt < 3; ++mt) {
            f32x4 a = {0.f, 0.f, 0.f, 0.f};
            #pragma unroll
            for (int ks = 0; ks < 4; ++ks) {
                bf16x8 af = *(const bf16x8*)(H1 + (mt * 16 + l15) * 136 + ks * 32 + quad * 8);
                a = __builtin_amdgcn_mfma_f32_16x16x32_bf16(af, Bw1[ks], a, 0, 0, 0);
            }
            acc1[mt] = a;
        }
        __syncthreads();                         // C: all H1 reads done
        // writeback KB = gelu(acc1 + b) in-place into H1
        #pragma unroll
        for (int mt = 0; mt < 3; ++mt)
            #pragma unroll
            for (int rg = 0; rg < 4; ++rg) {
                int row = mt * 16 + quad * 4 + rg;
                H1[row * 136 + w * 16 + l15] = (__bf16)gelu_f(acc1[mt][rg] + b2v);
            }
        __syncthreads();                         // D
        // GEMM2: acc2 = KB @ Wk[l]
        f32x4 acc2[3];
        #pragma unroll
        for (int mt = 0; mt < 3; ++mt) {
            f32x4 a = {0.f, 0.f, 0.f, 0.f};
            #pragma unroll
            for (int ks = 0; ks < 4; ++ks) {
                bf16x8 af = *(const bf16x8*)(H1 + (mt * 16 + l15) * 136 + ks * 32 + quad * 8);
                a = __builtin_amdgcn_mfma_f32_16x16x32_bf16(af, Bw2[ks], a, 0, 0, 0);
            }
            acc2[mt] = a;
        }
        // epilogue from C-layout: msg = h_bf[send]*k, ds_add (swizzled)
        int ecnt = cnt - tile * 4;
        if (ecnt > 4) ecnt = 4;
        int col = w * 16 + l15;
        #pragma unroll
        for (int mt = 0; mt < 3; ++mt)
            #pragma unroll
            for (int rg = 0; rg < 4; ++rg) {
                int row = mt * 16 + quad * 4 + rg;
                int el = row / 12, g = row - el * 12;
                if (el < ecnt) {
                    float hv = (float)h_bf[((size_t)sendS[el] * 12 + g) * 128 + col];
                    int scol = (col + g * 16) & 127;
                    atomicAdd(&aggS[(nlS[el] * 12 + g) * 128 + scol], acc2[mt][rg] * hv);
                }
            }
    }
    __syncthreads();
    for (int i = t; i < NPB * 1536; i += 512) {
        int row = i >> 7, cc = i & 127;
        int g = row - (row / 12) * 12;
        agg[(size_t)n0 * 1536 + i] = aggS[(row << 7) + ((cc + g * 16) & 127)];
    }
}

// ---------------- per-layer fused node kernel: conv + LN + MFMA MLP (2-pass) ----------------
__global__ __launch_bounds__(256, 4) void k_mlp(
    const float* __restrict__ agg, const float* __restrict__ fkl,
    const float* __restrict__ bconv, const float* __restrict__ ln_g,
    const float* __restrict__ ln_b,
    const __bf16* __restrict__ W1T, const float* __restrict__ b1,
    const __bf16* __restrict__ W2T2, const float* __restrict__ b2,
    const float* __restrict__ Wro, const float* __restrict__ bro,
    __bf16* __restrict__ h_bf, float* __restrict__ readout) {
    __shared__ __align__(16) __bf16 X[48 * 136];
    __shared__ __align__(16) __bf16 HIDh[48 * 264];   // half of HID (256 cols)
    __shared__ float redS[48][2];
    int t = threadIdx.x;
    int lane = t & 63, w = t >> 6, l15 = lane & 15, quad = lane >> 4;
    int c = t & 127, nh = t >> 7;
    int n0 = blockIdx.x * MNPB;
    // conv: x2[p,c] = sum_o agg[o,c]*fk[p,o,c]/12 + bconv[c]
    float bcv = bconv[c];
    #pragma unroll
    for (int nn = nh; nn < 4; nn += 2) {
        float a[12];
        #pragma unroll
        for (int o = 0; o < 12; ++o)
            a[o] = agg[((size_t)(n0 + nn) * 12 + o) * 128 + c];
        #pragma unroll
        for (int p = 0; p < 12; ++p) {
            float s = 0.f;
            #pragma unroll
            for (int o = 0; o < 12; ++o) s += a[o] * fkl[(p * 12 + o) * 128 + c];
            X[(nn * 12 + p) * 136 + c] = (__bf16)(s * (1.0f / 12.0f) + bcv);
        }
    }
    __syncthreads();
    // LN stats: wave w rows [w*12, w*12+12)
    for (int r = w * 12; r < w * 12 + 12; ++r) {
        float v0 = (float)X[r * 136 + lane];
        float v1 = (float)X[r * 136 + 64 + lane];
        float s = v0 + v1, s2 = v0 * v0 + v1 * v1;
        for (int off = 32; off > 0; off >>= 1) {
            s += __shfl_down(s, off);
            s2 += __shfl_down(s2, off);
        }
        if (lane == 0) {
            float mu = s * (1.0f / 128.0f);
            float var = s2 * (1.0f / 128.0f) - mu * mu;
            redS[r][0] = mu;
            redS[r][1] = rsqrtf(var + 1e-5f);
        }
    }
    __syncthreads();
    float gv = ln_g[c], bv = ln_b[c];
    #pragma unroll
    for (int nn = nh; nn < 4; nn += 2)
        #pragma unroll
        for (int p = 0; p < 12; ++p) {
            int r = nn * 12 + p;
            float v = (float)X[r * 136 + c];
            X[r * 136 + c] = (__bf16)((v - redS[r][0]) * redS[r][1] * gv + bv);
        }
    __syncthreads();
    // two-pass MLP: HID cols [256p,256p+256) staged, GEMM2 accumulates
    f32x4 acc2[3][2];
    #pragma unroll
    for (int mt = 0; mt < 3; ++mt)
        #pragma unroll
        for (int j = 0; j < 2; ++j) acc2[mt][j] = (f32x4){0.f, 0.f, 0.f, 0.f};
    for (int p = 0; p < 2; ++p) {
        if (p) __syncthreads();                  // HIDh WAR
        // GEMM1 pass p: wave w -> local cols [64w, 64w+64)
        #pragma unroll
        for (int mt = 0; mt < 3; ++mt) {
            bf16x8 af[4];
            #pragma unroll
            for (int ks = 0; ks < 4; ++ks)
                af[ks] = *(const bf16x8*)(X + (mt * 16 + l15) * 136 + ks * 32 + quad * 8);
            #pragma unroll
            for (int nt = 0; nt < 4; ++nt) {
                int colf = p * 256 + w * 64 + nt * 16 + l15;
                f32x4 a = {0.f, 0.f, 0.f, 0.f};
                #pragma unroll
                for (int ks = 0; ks < 4; ++ks) {
                    bf16x8 bf = *(const bf16x8*)(W1T + (size_t)colf * 128 + ks * 32 + quad * 8);
                    a = __builtin_amdgcn_mfma_f32_16x16x32_bf16(af[ks], bf, a, 0, 0, 0);
                }
                float bj = b1[colf];
                #pragma unroll
                for (int rg = 0; rg < 4; ++rg) {
                    int row = mt * 16 + quad * 4 + rg;
                    HIDh[row * 264 + w * 64 + nt * 16 + l15] = (__bf16)gelu_f(a[rg] + bj);
                }
            }
        }
        __syncthreads();
        // GEMM2 partial over k chunk [256p,256p+256): wave w -> cols [32w,32w+32)
        #pragma unroll
        for (int mt = 0; mt < 3; ++mt)
            #pragma unroll
            for (int ks = 0; ks < 8; ++ks) {
                bf16x8 af = *(const bf16x8*)(HIDh + (mt * 16 + l15) * 264 + ks * 32 + quad * 8);
                #pragma unroll
                for (int j = 0; j < 2; ++j) {
                    int col = w * 32 + j * 16 + l15;
                    bf16x8 bf = *(const bf16x8*)(W2T2 + (size_t)col * 512 + p * 256 + ks * 32 + quad * 8);
                    acc2[mt][j] = __builtin_amdgcn_mfma_f32_16x16x32_bf16(af, bf, acc2[mt][j], 0, 0, 0);
                }
            }
    }
    // residual + h write + stage for readout
    #pragma unroll
    for (int mt = 0; mt < 3; ++mt) {
        float bj0 = b2[w * 32 + l15], bj1 = b2[w * 32 + 16 + l15];
        #pragma unroll
        for (int rg = 0; rg < 4; ++rg) {
            int row = mt * 16 + quad * 4 + rg;
            int node = n0 + row / 12, pp = row % 12;
            size_t hi = ((size_t)node * 12 + pp) * 128;
            {
                int col = w * 32 + l15;
                float hv = (float)h_bf[hi + col] + acc2[mt][0][rg] + bj0;
                h_bf[hi + col] = (__bf16)hv;
                X[row * 136 + col] = (__bf16)hv;
            }
            {
                int col = w * 32 + 16 + l15;
                float hv = (float)h_bf[hi + col] + acc2[mt][1][rg] + bj1;
                h_bf[hi + col] = (__bf16)hv;
                X[row * 136 + col] = (__bf16)hv;
            }
        }
    }
    __syncthreads();
    // readout += (h @ Wro + bro)/3
    for (int idx = t; idx < 432; idx += 256) {
        int row = idx / 9, j = idx % 9;
        float s = 0.f;
        for (int cc = 0; cc < 128; ++cc) s += (float)X[row * 136 + cc] * Wro[cc * 9 + j];
        int node = n0 + row / 12, pp = row % 12;
        readout[((size_t)node * 12 + pp) * 9 + j] += (s + bro[j]) * (1.0f / 3.0f);
    }
}

// ---------------- final pooling ----------------
__global__ __launch_bounds__(128) void k_out(
    const float* __restrict__ readout, const float* __restrict__ node_grid,
    const int* __restrict__ batch, float* __restrict__ out) {
    int n = blockIdx.x * 128 + threadIdx.x;
    if (n >= N_NODES) return;
    int b = batch[n];
    const float* ro = readout + (size_t)n * 108;
    float ss[8] = {0, 0, 0, 0, 0, 0, 0, 0};
    float v0 = 0.f, v1 = 0.f, v2 = 0.f;
    for (int p = 0; p < 12; ++p) {
        #pragma unroll
        for (int j = 0; j < 8; ++j) ss[j] += ro[p * 9 + j];
        float rv = ro[p * 9 + 8];
        v0 += rv * node_grid[n * 36 + p * 3 + 0];
        v1 += rv * node_grid[n * 36 + p * 3 + 1];
        v2 += rv * node_grid[n * 36 + p * 3 + 2];
    }
    #pragma unroll
    for (int j = 0; j < 8; ++j) atomicAdd(&out[b * 8 + j], ss[j] * (1.0f / 12.0f));
    atomicAdd(&out[512 + b * 3 + 0], v0 * (1.0f / 12.0f));
    atomicAdd(&out[512 + b * 3 + 1], v1 * (1.0f / 12.0f));
    atomicAdd(&out[512 + b * 3 + 2], v2 * (1.0f / 12.0f));
}

extern "C" void kernel_launch(void* const* d_in, const int* in_sizes, int n_in,
                              void* d_out, int out_size, void* d_ws, size_t ws_size,
                              hipStream_t stream) {
    const float* x    = (const float*)d_in[0];
    const float* vec  = (const float*)d_in[1];
    const float* pos  = (const float*)d_in[2];
    const float* Q    = (const float*)d_in[3];
    const float* Wsp1 = (const float*)d_in[4];
    const float* bsp1 = (const float*)d_in[5];
    const float* Wsp2 = (const float*)d_in[6];
    const float* bsp2 = (const float*)d_in[7];
    const float* Wsh1 = (const float*)d_in[8];
    const float* bsh1 = (const float*)d_in[9];
    const float* Wsh2 = (const float*)d_in[10];
    const float* bsh2 = (const float*)d_in[11];
    const float* Wemb = (const float*)d_in[12];
    const float* Wk   = (const float*)d_in[13];
    const float* Wfk  = (const float*)d_in[14];
    const float* bconv= (const float*)d_in[15];
    const float* ln_g = (const float*)d_in[16];
    const float* ln_b = (const float*)d_in[17];
    const float* W1   = (const float*)d_in[18];
    const float* b1   = (const float*)d_in[19];
    const float* W2   = (const float*)d_in[20];
    const float* b2   = (const float*)d_in[21];
    const float* Wro  = (const float*)d_in[22];
    const float* bro  = (const float*)d_in[23];
    const int* ei     = (const int*)d_in[24];
    const int* batch  = (const int*)d_in[25];
    const int* send = ei;
    const int* recv = ei + N_EDGES;

    // workspace layout (float slots) — total 21,559,504 floats = 86.2 MB
    float* ws     = (float*)d_ws;
    float* grid0  = ws;                        // 64
    float* grid   = ws + 64;                   // 2304
    float* fk     = ws + 2368;                 // 55296
    float* ng     = ws + 57664;                // 288000
    float* ro     = ws + 345664;               // 864000
    float* attr_s = ws + 1209664;              // 1536384
    float* agg    = ws + 2746048;              // 12288000
    __bf16* WT    = (__bf16*)(ws + 15034048);  // 7*65536 bf16 = 229376 floats
    __bf16* h_bf  = (__bf16*)(ws + 15263424);  // 12288000 bf16 = 6144000 floats
    int*   ibase  = (int*)(ws + 21407424);
    int* deg    = ibase;            // 8000
    int* cursor = ibase + 8000;     // 8000
    int* rowptr = ibase + 16000;    // 8064
    int* perm   = ibase + 24064;    // 64000
    int* send_s = ibase + 88064;    // 64016
    const size_t NEED = 21559504ull * 4ull;
    if (ws_size < NEED) return;

    const __bf16* Wsp2T = WT;
    const __bf16* WkT   = WT + 16384;
    const __bf16* W1T   = WT + 65536;
    const __bf16* W2T   = WT + 65536 + 3 * 65536;

    hipMemsetAsync(d_out, 0, sizeof(float) * (size_t)out_size, stream);
    hipMemsetAsync(ro, 0, sizeof(float) * 864000, stream);
    hipMemsetAsync(deg, 0, sizeof(int) * 8000, stream);

    k_grid<<<1, 256, 0, stream>>>(Q, grid0, grid);
    k_kbsh<<<144, 128, 0, stream>>>(grid0, Wsh1, bsh1, Wsh2, bsh2, Wfk, fk);
    k_embed<<<N_NODES, 128, 0, stream>>>(x, vec, batch, grid, Wemb, ng, h_bf);
    k_deg<<<250, 256, 0, stream>>>(recv, deg);
    k_scan<<<1, 1024, 0, stream>>>(deg, rowptr, cursor);
    k_fill<<<250, 256, 0, stream>>>(recv, cursor, perm);
    k_attr_sorted<<<((N_EDGES + 16) * 12 + 255) / 256, 256, 0, stream>>>(
        pos, ng, send, recv, perm, attr_s, send_s);
    k_prepw2<<<(7 * 65536 + 255) / 256, 256, 0, stream>>>(Wsp2, Wk, W1, W2, WT);

    for (int l = 0; l < 3; ++l) {
        k_edge3<<<N_NODES / NPB, 512, 0, stream>>>(attr_s, send_s, rowptr,
            Wsp2T, WkT + l * 16384, Wsp1, bsp1, bsp2, h_bf, agg);
        k_mlp<<<N_NODES / MNPB, 256, 0, stream>>>(agg, fk + l * 18432,
            bconv + l * 128, ln_g + l * 128, ln_b + l * 128,
            W1T + l * 65536, b1 + l * 512, W2T + l * 65536, b2 + l * 128,
            Wro + l * 1152, bro + l * 9, h_bf, ro);
    }
    k_out<<<(N_NODES + 127) / 128, 128, 0, stream>>>(ro, ng, batch, (float*)d_out);
}

// Round 7
// 2103.760 us; speedup vs baseline: 2.7220x; 1.4760x over previous
//
#include <hip/hip_runtime.h>
#include <hip/hip_bf16.h>

#define N_NODES 8000
#define N_EDGES 64000
#define NBATCH  64
#define NGRID   12
#define HIDC    128
#define MNPB    4        // nodes per mlp-block
#define CH      6400     // edges per k-chunk
#define NCHUNK  10
#define RING_E  (2*CH)   // ring capacity (edges)

typedef __bf16 bf16x8 __attribute__((ext_vector_type(8)));
typedef float  f32x4  __attribute__((ext_vector_type(4)));

// tanh-form GELU
__device__ __forceinline__ float gelu_f(float x) {
    float u = 0.7978845608f * x * (1.0f + 0.044715f * x * x);
    float e = __expf(2.0f * u);
    float t = 1.0f - 2.0f / (e + 1.0f);
    return 0.5f * x * (1.0f + t);
}

// ---------------- grid0 + per-batch rotated grids ----------------
__global__ void k_grid(const float* __restrict__ Q, float* __restrict__ grid0,
                       float* __restrict__ grid) {
    int t = threadIdx.x;
    __shared__ float g0[12][3];
    if (t < 12) {
        float fi = (float)t;
        float theta = 6.28318530717958647692f * fi / 1.61803398874989484820f;
        float z = 1.0f - (2.0f * fi + 1.0f) / 12.0f;
        float r = sqrtf(fmaxf(1.0f - z * z, 0.0f));
        g0[t][0] = r * cosf(theta);
        g0[t][1] = r * sinf(theta);
        g0[t][2] = z;
        grid0[t * 3 + 0] = g0[t][0];
        grid0[t * 3 + 1] = g0[t][1];
        grid0[t * 3 + 2] = g0[t][2];
    }
    __syncthreads();
    for (int idx = t; idx < NBATCH * 12 * 3; idx += blockDim.x) {
        int b = idx / 36, rmd = idx % 36, n = rmd / 3, i = rmd % 3;
        float acc = 0.f;
        #pragma unroll
        for (int j = 0; j < 3; ++j) acc += Q[b * 9 + i * 3 + j] * g0[n][j];
        grid[idx] = acc;
    }
}

// ---------------- kb_sh -> fk  (3,12,12,128) ----------------
__global__ __launch_bounds__(128) void k_kbsh(
    const float* __restrict__ grid0,
    const float* __restrict__ Wsh1, const float* __restrict__ bsh1,
    const float* __restrict__ Wsh2, const float* __restrict__ bsh2,
    const float* __restrict__ Wfk, float* __restrict__ fk) {
    int row = blockIdx.x;            // p*12+o
    int p = row / 12, o = row % 12, t = threadIdx.x;
    float tt = grid0[p*3]*grid0[o*3] + grid0[p*3+1]*grid0[o*3+1] + grid0[p*3+2]*grid0[o*3+2];
    float p1 = tt, p2 = tt * tt, p3 = p2 * tt;
    float h1 = gelu_f(p1 * Wsh1[t] + p2 * Wsh1[128 + t] + p3 * Wsh1[256 + t] + bsh1[t]);
    __shared__ float h1S[128];
    __shared__ float h2S[128];
    h1S[t] = h1;
    __syncthreads();
    float acc = bsh2[t];
    #pragma unroll 8
    for (int k = 0; k < 128; ++k) acc += h1S[k] * Wsh2[k * 128 + t];
    h2S[t] = gelu_f(acc);
    __syncthreads();
    for (int l = 0; l < 3; ++l) {
        float a = 0.f;
        #pragma unroll 8
        for (int k = 0; k < 128; ++k) a += h2S[k] * Wfk[l * 16384 + k * 128 + t];
        fk[l * 18432 + row * 128 + t] = a;
    }
}

// ---------------- node_grid + h0 = f @ Wemb (h stored bf16) ----------------
__global__ __launch_bounds__(128) void k_embed(
    const float* __restrict__ x, const float* __restrict__ vec,
    const int* __restrict__ batch, const float* __restrict__ grid,
    const float* __restrict__ Wemb, float* __restrict__ node_grid,
    __bf16* __restrict__ h_bf) {
    __shared__ float WembS[18 * 128];
    __shared__ float ngS[36];
    __shared__ float xS[16];
    __shared__ float vS[6];
    int n = blockIdx.x, t = threadIdx.x;
    for (int i = t; i < 18 * 128; i += 128) WembS[i] = Wemb[i];
    int b = batch[n];
    if (t < 36) { float g = grid[b * 36 + t]; ngS[t] = g; node_grid[n * 36 + t] = g; }
    if (t < 16) xS[t] = x[n * 16 + t];
    if (t >= 16 && t < 22) vS[t - 16] = vec[n * 6 + (t - 16)];
    __syncthreads();
    for (int g = 0; g < NGRID; ++g) {
        float g0 = ngS[g*3], g1 = ngS[g*3+1], g2 = ngS[g*3+2];
        float xv0 = vS[0]*g0 + vS[1]*g1 + vS[2]*g2;
        float xv1 = vS[3]*g0 + vS[4]*g1 + vS[5]*g2;
        float acc = xv0 * WembS[16*128 + t] + xv1 * WembS[17*128 + t];
        #pragma unroll
        for (int j = 0; j < 16; ++j) acc += xS[j] * WembS[j*128 + t];
        h_bf[((size_t)n * NGRID + g) * HIDC + t] = (__bf16)acc;
    }
}

// ---------------- CSR build ----------------
__global__ __launch_bounds__(256) void k_deg(const int* __restrict__ recv,
                                             int* __restrict__ deg) {
    int e = blockIdx.x * 256 + threadIdx.x;
    if (e < N_EDGES) atomicAdd(&deg[recv[e]], 1);
}

__global__ __launch_bounds__(1024) void k_scan(const int* __restrict__ deg,
                                               int* __restrict__ rowptr,
                                               int* __restrict__ cursor) {
    __shared__ int part[1024];
    int t = threadIdx.x;
    int base = t * 8;
    int local[8];
    int s = 0;
    #pragma unroll
    for (int j = 0; j < 8; ++j) {
        int idx = base + j;
        int v = (idx < N_NODES) ? deg[idx] : 0;
        local[j] = s;
        s += v;
    }
    part[t] = s;
    __syncthreads();
    for (int off = 1; off < 1024; off <<= 1) {
        int v = (t >= off) ? part[t - off] : 0;
        __syncthreads();
        part[t] += v;
        __syncthreads();
    }
    int excl = (t == 0) ? 0 : part[t - 1];
    #pragma unroll
    for (int j = 0; j < 8; ++j) {
        int idx = base + j;
        if (idx < N_NODES) {
            int v = excl + local[j];
            rowptr[idx] = v;
            cursor[idx] = v;
        }
    }
    if (t == 1023) rowptr[N_NODES] = part[1023];
}

__global__ __launch_bounds__(256) void k_fill(const int* __restrict__ recv,
                                              int* __restrict__ cursor,
                                              int* __restrict__ perm) {
    int e = blockIdx.x * 256 + threadIdx.x;
    if (e < N_EDGES) {
        int r = recv[e];
        int p = atomicAdd(&cursor[r], 1);
        perm[p] = e;
    }
}

// ---------------- per-(sorted-edge,grid) invariants + sorted send ----------------
__global__ __launch_bounds__(256) void k_attr_sorted(
    const float* __restrict__ pos, const float* __restrict__ ng,
    const int* __restrict__ send, const int* __restrict__ recv,
    const int* __restrict__ perm,
    float* __restrict__ attr_s, int* __restrict__ send_s) {
    int idx = blockIdx.x * 256 + threadIdx.x;
    if (idx >= (N_EDGES + 16) * 12) return;
    int i = idx / 12, g = idx % 12;
    if (i < N_EDGES) {
        int e = perm[i];
        int s = send[e], r = recv[e];
        float rx = pos[s*3+0] - pos[r*3+0];
        float ry = pos[s*3+1] - pos[r*3+1];
        float rz = pos[s*3+2] - pos[r*3+2];
        const float* gr = ng + ((size_t)r * 12 + g) * 3;
        float g0 = gr[0], g1 = gr[1], g2 = gr[2];
        float iv1 = rx*g0 + ry*g1 + rz*g2;
        float wx = rx - iv1*g0, wy = ry - iv1*g1, wz = rz - iv1*g2;
        attr_s[(size_t)idx * 2 + 0] = iv1;
        attr_s[(size_t)idx * 2 + 1] = sqrtf(wx*wx + wy*wy + wz*wz);
        if (g == 0) send_s[i] = s;
    } else {
        attr_s[(size_t)idx * 2 + 0] = 0.f;
        attr_s[(size_t)idx * 2 + 1] = 0.f;
        if (g == 0) send_s[i] = 0;
    }
}

// ---- transposed bf16 weights: [Wsp2T | WkT l=0..2 | W1T l=0..2 | W2T l=0..2] ----
__global__ __launch_bounds__(256) void k_prepw2(
    const float* __restrict__ Wsp2, const float* __restrict__ Wk,
    const float* __restrict__ W1, const float* __restrict__ W2,
    __bf16* __restrict__ WT) {
    int i = blockIdx.x * 256 + threadIdx.x;
    if (i >= 7 * 65536) return;
    float v;
    if (i < 65536) {
        int buf = i >> 14, r = i & 16383;
        int n = r >> 7, k = r & 127;
        v = (buf == 0) ? Wsp2[k * 128 + n] : Wk[(buf - 1) * 16384 + k * 128 + n];
    } else {
        int i2 = i - 65536;
        int l = i2 >> 16, r = i2 & 65535;
        if (l < 3) {                  // W1T[l]: [512 n x 128 k]
            int n = r >> 7, k = r & 127;
            v = W1[l * 65536 + k * 512 + n];
        } else {                      // W2T[l]: [128 n x 512 k]
            int l2 = l - 3;
            int n = r >> 9, k = r & 511;
            v = W2[l2 * 65536 + k * 128 + n];
        }
    }
    WT[i] = (__bf16)v;
}

// ---------------- dense k kernel: poly -> GEMM1 -> GEMM2 -> k (ring, bf16) ----------------
// One 64-row tile per block (rows = (edge,grid) flattened, chunk of CH edges).
// No gathers, no atomics, no CSR. Wave w owns cols [32w,32w+32).
__global__ __launch_bounds__(256, 4) void k_kdense(
    const float* __restrict__ attr_s,
    const __bf16* __restrict__ W2T, const __bf16* __restrict__ WkTl,
    const float* __restrict__ Wsp1, const float* __restrict__ bsp1,
    const float* __restrict__ bsp2,
    int chunk, __bf16* __restrict__ kring) {
    __shared__ __align__(16) __bf16 H1[64 * 136];
    int t = threadIdx.x;
    int lane = t & 63, w = t >> 6, l15 = lane & 15, quad = lane >> 4;
    int c = t & 127, rh = t >> 7;
    size_t grow0 = (size_t)chunk * (CH * 12) + (size_t)blockIdx.x * 64;
    // per-column poly weights (combined poly_features duplicates)
    float w_a, w_b, w_aa, w_ab, w_bb, w_aaa, w_aab, w_abb, w_bbb, b1v;
    {
        float w1[14];
        #pragma unroll
        for (int j = 0; j < 14; ++j) w1[j] = Wsp1[j * 128 + c];
        w_a = w1[0]; w_b = w1[1];
        w_aa = w1[2]; w_ab = w1[3] + w1[4]; w_bb = w1[5];
        w_aaa = w1[6]; w_aab = w1[7] + w1[8] + w1[10];
        w_abb = w1[9] + w1[11] + w1[12]; w_bbb = w1[13];
        b1v = bsp1[c];
    }
    // poly -> h1 bf16: thread owns col c, rows rh*32..rh*32+32
    const float2* ap = (const float2*)attr_s + grow0 + rh * 32;
    #pragma unroll 8
    for (int i = 0; i < 32; ++i) {
        float2 abv = ap[i];
        float a = abv.x, b = abv.y;
        float aa = a * a, ab = a * b, bb = b * b;
        float v = b1v + a * w_a + b * w_b + aa * w_aa + ab * w_ab + bb * w_bb
                + aa * a * w_aaa + aa * b * w_aab + bb * a * w_abb + bb * b * w_bbb;
        H1[(rh * 32 + i) * 136 + c] = (__bf16)gelu_f(v);
    }
    __syncthreads();
    // GEMM1: acc = H1 @ Wsp2, cols w*32 + j*16 + l15
    bf16x8 Bf[2][4];
    #pragma unroll
    for (int j = 0; j < 2; ++j)
        #pragma unroll
        for (int ks = 0; ks < 4; ++ks)
            Bf[j][ks] = *(const bf16x8*)(W2T + (size_t)(w * 32 + j * 16 + l15) * 128 + ks * 32 + quad * 8);
    float b2v[2] = { bsp2[w * 32 + l15], bsp2[w * 32 + 16 + l15] };
    f32x4 acc[4][2];
    #pragma unroll
    for (int mt = 0; mt < 4; ++mt) {
        acc[mt][0] = (f32x4){0.f,0.f,0.f,0.f};
        acc[mt][1] = (f32x4){0.f,0.f,0.f,0.f};
        #pragma unroll
        for (int ks = 0; ks < 4; ++ks) {
            bf16x8 af = *(const bf16x8*)(H1 + (mt * 16 + l15) * 136 + ks * 32 + quad * 8);
            acc[mt][0] = __builtin_amdgcn_mfma_f32_16x16x32_bf16(af, Bf[0][ks], acc[mt][0], 0, 0, 0);
            acc[mt][1] = __builtin_amdgcn_mfma_f32_16x16x32_bf16(af, Bf[1][ks], acc[mt][1], 0, 0, 0);
        }
    }
    __syncthreads();
    // writeback KB = gelu(acc + b) in-place
    #pragma unroll
    for (int mt = 0; mt < 4; ++mt)
        #pragma unroll
        for (int j = 0; j < 2; ++j)
            #pragma unroll
            for (int rg = 0; rg < 4; ++rg) {
                int row = mt * 16 + quad * 4 + rg;
                H1[row * 136 + w * 32 + j * 16 + l15] = (__bf16)gelu_f(acc[mt][j][rg] + b2v[j]);
            }
    __syncthreads();
    // GEMM2: k = KB @ Wk[l]
    #pragma unroll
    for (int j = 0; j < 2; ++j)
        #pragma unroll
        for (int ks = 0; ks < 4; ++ks)
            Bf[j][ks] = *(const bf16x8*)(WkTl + (size_t)(w * 32 + j * 16 + l15) * 128 + ks * 32 + quad * 8);
    #pragma unroll
    for (int mt = 0; mt < 4; ++mt) {
        acc[mt][0] = (f32x4){0.f,0.f,0.f,0.f};
        acc[mt][1] = (f32x4){0.f,0.f,0.f,0.f};
        #pragma unroll
        for (int ks = 0; ks < 4; ++ks) {
            bf16x8 af = *(const bf16x8*)(H1 + (mt * 16 + l15) * 136 + ks * 32 + quad * 8);
            acc[mt][0] = __builtin_amdgcn_mfma_f32_16x16x32_bf16(af, Bf[0][ks], acc[mt][0], 0, 0, 0);
            acc[mt][1] = __builtin_amdgcn_mfma_f32_16x16x32_bf16(af, Bf[1][ks], acc[mt][1], 0, 0, 0);
        }
    }
    __syncthreads();
    #pragma unroll
    for (int mt = 0; mt < 4; ++mt)
        #pragma unroll
        for (int j = 0; j < 2; ++j)
            #pragma unroll
            for (int rg = 0; rg < 4; ++rg) {
                int row = mt * 16 + quad * 4 + rg;
                H1[row * 136 + w * 32 + j * 16 + l15] = (__bf16)acc[mt][j][rg];
            }
    __syncthreads();
    // coalesced ring store: 64 rows x 128 cols bf16 as 16B vectors
    size_t rr0 = (size_t)(chunk & 1) * (CH * 12) + (size_t)blockIdx.x * 64;
    #pragma unroll
    for (int it = 0; it < 4; ++it) {
        int idx = it * 256 + t;           // 0..1023
        int row = idx >> 4, cv = idx & 15;
        *(uint4*)(kring + (rr0 + row) * 128 + cv * 8) =
            *(const uint4*)(H1 + row * 136 + cv * 8);
    }
}

// ---------------- scatter-reduce: per recv node, register accumulate ----------------
// Node n processed by the chunk containing its FIRST edge; reads may run into
// the next ring slot (node degree << CH). Plain stores, no atomics.
__global__ __launch_bounds__(128) void k_scat(
    const int* __restrict__ rowptr, const int* __restrict__ send_s,
    const __bf16* __restrict__ kring, const __bf16* __restrict__ h_bf,
    int elo, int ehi, __bf16* __restrict__ aggb) {
    int n = blockIdx.x;
    int e0 = rowptr[n], e1 = rowptr[n + 1];
    if (e0 < elo || e0 >= ehi) return;
    int t = threadIdx.x;
    float acc[12];
    #pragma unroll
    for (int j = 0; j < 12; ++j) acc[j] = 0.f;
    for (int e = e0; e < e1; ++e) {
        int s = send_s[e];
        const __bf16* hp = h_bf + (size_t)s * 1536;
        const __bf16* kp = kring + (size_t)(e % RING_E) * 1536;
        #pragma unroll
        for (int j = 0; j < 12; ++j) {
            int i = j * 128 + t;
            acc[j] += (float)hp[i] * (float)kp[i];
        }
    }
    #pragma unroll
    for (int j = 0; j < 12; ++j)
        aggb[(size_t)n * 1536 + j * 128 + t] = (__bf16)acc[j];
}

// ---------------- per-layer fused node kernel: conv + LN + MFMA MLP (2-pass) ----------------
__global__ __launch_bounds__(256, 4) void k_mlp(
    const __bf16* __restrict__ aggb, const float* __restrict__ fkl,
    const float* __restrict__ bconv, const float* __restrict__ ln_g,
    const float* __restrict__ ln_b,
    const __bf16* __restrict__ W1T, const float* __restrict__ b1,
    const __bf16* __restrict__ W2T2, const float* __restrict__ b2,
    const float* __restrict__ Wro, const float* __restrict__ bro,
    __bf16* __restrict__ h_bf, float* __restrict__ readout) {
    __shared__ __align__(16) __bf16 X[48 * 136];
    __shared__ __align__(16) __bf16 HIDh[48 * 264];   // half of HID (256 cols)
    __shared__ float redS[48][2];
    int t = threadIdx.x;
    int lane = t & 63, w = t >> 6, l15 = lane & 15, quad = lane >> 4;
    int c = t & 127, nh = t >> 7;
    int n0 = blockIdx.x * MNPB;
    float bcv = bconv[c];
    #pragma unroll
    for (int nn = nh; nn < 4; nn += 2) {
        float a[12];
        #pragma unroll
        for (int o = 0; o < 12; ++o)
            a[o] = (float)aggb[((size_t)(n0 + nn) * 12 + o) * 128 + c];
        #pragma unroll
        for (int p = 0; p < 12; ++p) {
            float s = 0.f;
            #pragma unroll
            for (int o = 0; o < 12; ++o) s += a[o] * fkl[(p * 12 + o) * 128 + c];
            X[(nn * 12 + p) * 136 + c] = (__bf16)(s * (1.0f / 12.0f) + bcv);
        }
    }
    __syncthreads();
    for (int r = w * 12; r < w * 12 + 12; ++r) {
        float v0 = (float)X[r * 136 + lane];
        float v1 = (float)X[r * 136 + 64 + lane];
        float s = v0 + v1, s2 = v0 * v0 + v1 * v1;
        for (int off = 32; off > 0; off >>= 1) {
            s += __shfl_down(s, off);
            s2 += __shfl_down(s2, off);
        }
        if (lane == 0) {
            float mu = s * (1.0f / 128.0f);
            float var = s2 * (1.0f / 128.0f) - mu * mu;
            redS[r][0] = mu;
            redS[r][1] = rsqrtf(var + 1e-5f);
        }
    }
    __syncthreads();
    float gv = ln_g[c], bv = ln_b[c];
    #pragma unroll
    for (int nn = nh; nn < 4; nn += 2)
        #pragma unroll
        for (int p = 0; p < 12; ++p) {
            int r = nn * 12 + p;
            float v = (float)X[r * 136 + c];
            X[r * 136 + c] = (__bf16)((v - redS[r][0]) * redS[r][1] * gv + bv);
        }
    __syncthreads();
    f32x4 acc2[3][2];
    #pragma unroll
    for (int mt = 0; mt < 3; ++mt)
        #pragma unroll
        for (int j = 0; j < 2; ++j) acc2[mt][j] = (f32x4){0.f, 0.f, 0.f, 0.f};
    for (int p = 0; p < 2; ++p) {
        if (p) __syncthreads();
        #pragma unroll
        for (int mt = 0; mt < 3; ++mt) {
            bf16x8 af[4];
            #pragma unroll
            for (int ks = 0; ks < 4; ++ks)
                af[ks] = *(const bf16x8*)(X + (mt * 16 + l15) * 136 + ks * 32 + quad * 8);
            #pragma unroll
            for (int nt = 0; nt < 4; ++nt) {
                int colf = p * 256 + w * 64 + nt * 16 + l15;
                f32x4 a = {0.f, 0.f, 0.f, 0.f};
                #pragma unroll
                for (int ks = 0; ks < 4; ++ks) {
                    bf16x8 bf = *(const bf16x8*)(W1T + (size_t)colf * 128 + ks * 32 + quad * 8);
                    a = __builtin_amdgcn_mfma_f32_16x16x32_bf16(af[ks], bf, a, 0, 0, 0);
                }
                float bj = b1[colf];
                #pragma unroll
                for (int rg = 0; rg < 4; ++rg) {
                    int row = mt * 16 + quad * 4 + rg;
                    HIDh[row * 264 + w * 64 + nt * 16 + l15] = (__bf16)gelu_f(a[rg] + bj);
                }
            }
        }
        __syncthreads();
        #pragma unroll
        for (int mt = 0; mt < 3; ++mt)
            #pragma unroll
            for (int ks = 0; ks < 8; ++ks) {
                bf16x8 af = *(const bf16x8*)(HIDh + (mt * 16 + l15) * 264 + ks * 32 + quad * 8);
                #pragma unroll
                for (int j = 0; j < 2; ++j) {
                    int col = w * 32 + j * 16 + l15;
                    bf16x8 bf = *(const bf16x8*)(W2T2 + (size_t)col * 512 + p * 256 + ks * 32 + quad * 8);
                    acc2[mt][j] = __builtin_amdgcn_mfma_f32_16x16x32_bf16(af, bf, acc2[mt][j], 0, 0, 0);
                }
            }
    }
    #pragma unroll
    for (int mt = 0; mt < 3; ++mt) {
        float bj0 = b2[w * 32 + l15], bj1 = b2[w * 32 + 16 + l15];
        #pragma unroll
        for (int rg = 0; rg < 4; ++rg) {
            int row = mt * 16 + quad * 4 + rg;
            int node = n0 + row / 12, pp = row % 12;
            size_t hi = ((size_t)node * 12 + pp) * 128;
            {
                int col = w * 32 + l15;
                float hv = (float)h_bf[hi + col] + acc2[mt][0][rg] + bj0;
                h_bf[hi + col] = (__bf16)hv;
                X[row * 136 + col] = (__bf16)hv;
            }
            {
                int col = w * 32 + 16 + l15;
                float hv = (float)h_bf[hi + col] + acc2[mt][1][rg] + bj1;
                h_bf[hi + col] = (__bf16)hv;
                X[row * 136 + col] = (__bf16)hv;
            }
        }
    }
    __syncthreads();
    for (int idx = t; idx < 432; idx += 256) {
        int row = idx / 9, j = idx % 9;
        float s = 0.f;
        for (int cc = 0; cc < 128; ++cc) s += (float)X[row * 136 + cc] * Wro[cc * 9 + j];
        int node = n0 + row / 12, pp = row % 12;
        readout[((size_t)node * 12 + pp) * 9 + j] += (s + bro[j]) * (1.0f / 3.0f);
    }
}

// ---------------- final pooling ----------------
__global__ __launch_bounds__(128) void k_out(
    const float* __restrict__ readout, const float* __restrict__ node_grid,
    const int* __restrict__ batch, float* __restrict__ out) {
    int n = blockIdx.x * 128 + threadIdx.x;
    if (n >= N_NODES) return;
    int b = batch[n];
    const float* ro = readout + (size_t)n * 108;
    float ss[8] = {0, 0, 0, 0, 0, 0, 0, 0};
    float v0 = 0.f, v1 = 0.f, v2 = 0.f;
    for (int p = 0; p < 12; ++p) {
        #pragma unroll
        for (int j = 0; j < 8; ++j) ss[j] += ro[p * 9 + j];
        float rv = ro[p * 9 + 8];
        v0 += rv * node_grid[n * 36 + p * 3 + 0];
        v1 += rv * node_grid[n * 36 + p * 3 + 1];
        v2 += rv * node_grid[n * 36 + p * 3 + 2];
    }
    #pragma unroll
    for (int j = 0; j < 8; ++j) atomicAdd(&out[b * 8 + j], ss[j] * (1.0f / 12.0f));
    atomicAdd(&out[512 + b * 3 + 0], v0 * (1.0f / 12.0f));
    atomicAdd(&out[512 + b * 3 + 1], v1 * (1.0f / 12.0f));
    atomicAdd(&out[512 + b * 3 + 2], v2 * (1.0f / 12.0f));
}

extern "C" void kernel_launch(void* const* d_in, const int* in_sizes, int n_in,
                              void* d_out, int out_size, void* d_ws, size_t ws_size,
                              hipStream_t stream) {
    const float* x    = (const float*)d_in[0];
    const float* vec  = (const float*)d_in[1];
    const float* pos  = (const float*)d_in[2];
    const float* Q    = (const float*)d_in[3];
    const float* Wsp1 = (const float*)d_in[4];
    const float* bsp1 = (const float*)d_in[5];
    const float* Wsp2 = (const float*)d_in[6];
    const float* bsp2 = (const float*)d_in[7];
    const float* Wsh1 = (const float*)d_in[8];
    const float* bsh1 = (const float*)d_in[9];
    const float* Wsh2 = (const float*)d_in[10];
    const float* bsh2 = (const float*)d_in[11];
    const float* Wemb = (const float*)d_in[12];
    const float* Wk   = (const float*)d_in[13];
    const float* Wfk  = (const float*)d_in[14];
    const float* bconv= (const float*)d_in[15];
    const float* ln_g = (const float*)d_in[16];
    const float* ln_b = (const float*)d_in[17];
    const float* W1   = (const float*)d_in[18];
    const float* b1   = (const float*)d_in[19];
    const float* W2   = (const float*)d_in[20];
    const float* b2   = (const float*)d_in[21];
    const float* Wro  = (const float*)d_in[22];
    const float* bro  = (const float*)d_in[23];
    const int* ei     = (const int*)d_in[24];
    const int* batch  = (const int*)d_in[25];
    const int* send = ei;
    const int* recv = ei + N_EDGES;

    // workspace layout (float slots) — total 25,245,904 floats = 101.0 MB
    float* ws     = (float*)d_ws;
    float* grid0  = ws;                        // 64
    float* grid   = ws + 64;                   // 2304
    float* fk     = ws + 2368;                 // 55296
    float* ng     = ws + 57664;                // 288000
    float* ro     = ws + 345664;               // 864000
    float* attr_s = ws + 1209664;              // 1536384
    __bf16* WT    = (__bf16*)(ws + 2746048);   // 458752 bf16 = 229376 slots
    __bf16* h_bf  = (__bf16*)(ws + 2975424);   // 12288000 bf16 = 6144000 slots
    __bf16* aggb  = (__bf16*)(ws + 9119424);   // 12288000 bf16 = 6144000 slots
    __bf16* kring = (__bf16*)(ws + 15263424);  // 19660800 bf16 = 9830400 slots
    int*   ibase  = (int*)(ws + 25093824);
    int* deg    = ibase;            // 8000
    int* cursor = ibase + 8000;     // 8000
    int* rowptr = ibase + 16000;    // 8064
    int* perm   = ibase + 24064;    // 64000
    int* send_s = ibase + 88064;    // 64016
    const size_t NEED = 25245904ull * 4ull;
    if (ws_size < NEED) return;

    const __bf16* Wsp2T = WT;
    const __bf16* WkT   = WT + 16384;
    const __bf16* W1T   = WT + 65536;
    const __bf16* W2T   = WT + 65536 + 3 * 65536;

    hipMemsetAsync(d_out, 0, sizeof(float) * (size_t)out_size, stream);
    hipMemsetAsync(ro, 0, sizeof(float) * 864000, stream);
    hipMemsetAsync(deg, 0, sizeof(int) * 8000, stream);

    k_grid<<<1, 256, 0, stream>>>(Q, grid0, grid);
    k_kbsh<<<144, 128, 0, stream>>>(grid0, Wsh1, bsh1, Wsh2, bsh2, Wfk, fk);
    k_embed<<<N_NODES, 128, 0, stream>>>(x, vec, batch, grid, Wemb, ng, h_bf);
    k_deg<<<250, 256, 0, stream>>>(recv, deg);
    k_scan<<<1, 1024, 0, stream>>>(deg, rowptr, cursor);
    k_fill<<<250, 256, 0, stream>>>(recv, cursor, perm);
    k_attr_sorted<<<((N_EDGES + 16) * 12 + 255) / 256, 256, 0, stream>>>(
        pos, ng, send, recv, perm, attr_s, send_s);
    k_prepw2<<<(7 * 65536 + 255) / 256, 256, 0, stream>>>(Wsp2, Wk, W1, W2, WT);

    const int KB_BLOCKS = CH * 12 / 64;  // 1200 blocks per chunk
    for (int l = 0; l < 3; ++l) {
        const __bf16* WkTl = WkT + l * 16384;
        k_kdense<<<KB_BLOCKS, 256, 0, stream>>>(attr_s, Wsp2T, WkTl,
            Wsp1, bsp1, bsp2, 0, kring);
        for (int ck = 0; ck < NCHUNK; ++ck) {
            if (ck + 1 < NCHUNK)
                k_kdense<<<KB_BLOCKS, 256, 0, stream>>>(attr_s, Wsp2T, WkTl,
                    Wsp1, bsp1, bsp2, ck + 1, kring);
            int elo = ck * CH;
            int ehi = (ck == NCHUNK - 1) ? (N_EDGES + 1) : (elo + CH);
            k_scat<<<N_NODES, 128, 0, stream>>>(rowptr, send_s, kring, h_bf,
                elo, ehi, aggb);
        }
        k_mlp<<<N_NODES / MNPB, 256, 0, stream>>>(aggb, fk + l * 18432,
            bconv + l * 128, ln_g + l * 128, ln_b + l * 128,
            W1T + l * 65536, b1 + l * 512, W2T + l * 65536, b2 + l * 128,
            Wro + l * 1152, bro + l * 9, h_bf, ro);
    }
    k_out<<<(N_NODES + 127) / 128, 128, 0, stream>>>(ro, ng, batch, (float*)d_out);
}